// Round 10
// baseline (216.608 us; speedup 1.0000x reference)
//
#include <hip/hip_runtime.h>
#include <hip/hip_bf16.h>
#include <math.h>

// Problem constants (B=2, C=256, H=W=64, heads=8, hd=32, groups=32, hid=64)
#define NB 2
#define NC 256
#define NHEAD 8
#define HD 32
#define NPIX 4096
#define GEPS 1e-5f
#define NCHUNK 2          // j-split factor for attention (linear softmax => exact)
#define JLEN (NPIX / NCHUNK)

typedef short bf16x8 __attribute__((ext_vector_type(8)));
typedef float f32x4 __attribute__((ext_vector_type(4)));

typedef __attribute__((address_space(3))) unsigned int lds_u32;
typedef __attribute__((address_space(1))) const unsigned int glb_u32;

union U16x8 { uint4 u4; uint2 u2[2]; unsigned u32[4]; unsigned short us[8]; bf16x8 v; };

__device__ inline unsigned short tobf(float f) {  // round-to-nearest-even
  union { float f; unsigned u; } c; c.f = f;
  return (unsigned short)((c.u + 0x7FFFu + ((c.u >> 16) & 1u)) >> 16);
}
__device__ inline unsigned packtrunc(float lo, float hi) {  // truncating bf16 pack, 1 instr
  return __builtin_amdgcn_perm(__float_as_uint(hi), __float_as_uint(lo), 0x07060302u);
}
__device__ inline float geluf(float v) {
  return 0.5f * v * (1.f + erff(v * 0.70710678118654752f));
}
// gfx950 cross-lane swaps (MFMA-fragment redistribution primitives):
// P32: swap a[i+32]<->b[i]; P16: swap a[i+16]<->b[i] per 32-half.
__device__ inline void plane32(unsigned &a, unsigned &b) {
  asm("v_permlane32_swap_b32 %0, %1" : "+v"(a), "+v"(b));
}
__device__ inline void plane16(unsigned &a, unsigned &b) {
  asm("v_permlane16_swap_b32 %0, %1" : "+v"(a), "+v"(b));
}

// Per-block dtype self-detection (bf16 vs fp32 x): wave-0 ballot + broadcast.
__device__ inline int detect_bf(const void* xraw) {
  __shared__ int flg;
  int t = threadIdx.x;
  if (t < 64) {
    unsigned short h = ((const unsigned short*)xraw)[2 * t];
    unsigned e = (h >> 7) & 0xFFu;
    int weird = (e < 113u || e > 140u) ? 1 : 0;
    unsigned long long m = __ballot(weird);
    if (t == 0) flg = (__popcll(m) > 16) ? 0 : 1;
  }
  __syncthreads();
  return flg;
}

struct ConvArgs { const void* src[13]; int off[14]; };

__device__ inline float ldsrc(const void* p, int idx, int bf) {
  if (bf) {
    unsigned v = ((const unsigned short*)p)[idx];
    return __uint_as_float(v << 16);
  }
  return ((const float*)p)[idx];
}

// ---------------------------------------------------------------------------
// Fused convert + prep + GN1 block-partials (shfl reduction, r7).
// ---------------------------------------------------------------------------
__global__ __launch_bounds__(256) void conv_prep_kernel(
    ConvArgs a, float* __restrict__ dstbase, int total,
    unsigned short* __restrict__ wqkv_b, unsigned short* __restrict__ wout_b,
    unsigned short* __restrict__ wm1_b, unsigned short* __restrict__ wm2_b,
    float* __restrict__ qscale, float* __restrict__ part1p) {
  int bf = detect_bf(a.src[0]);
  int blk = blockIdx.x, t = threadIdx.x;
  int i = blk * 256 + t;
  float val = 0.f;
  if (i < total) {
    int s = 0;
    while (i >= a.off[s + 1]) ++s;
    val = ldsrc(a.src[s], i - a.off[s], bf);
    dstbase[i] = val;
  }
  // GN1 partials (x = segment 0, exactly blocks 0..8191)
  if (blk < 8192) {
    float s = val, s2 = val * val;
#pragma unroll
    for (int o = 32; o > 0; o >>= 1) {
      s += __shfl_down(s, o, 64);
      s2 += __shfl_down(s2, o, 64);
    }
    __shared__ float r4[4][2];
    if ((t & 63) == 0) { r4[t >> 6][0] = s; r4[t >> 6][1] = s2; }
    __syncthreads();
    if (t == 0) {
      part1p[blk * 2] = r4[0][0] + r4[1][0] + r4[2][0] + r4[3][0];
      part1p[blk * 2 + 1] = r4[0][1] + r4[1][1] + r4[2][1] + r4[3][1];
    }
  }
  // prep (reads raw sources)
  if (i < 196608) wqkv_b[i] = tobf(ldsrc(a.src[1], i, bf));
  else if (i < 262144) wout_b[i - 196608] = tobf(ldsrc(a.src[2], i - 196608, bf));
  else if (i < 278528) wm1_b[i - 262144] = tobf(ldsrc(a.src[9], i - 262144, bf));
  else if (i < 294912) wm2_b[i - 278528] = tobf(ldsrc(a.src[11], i - 278528, bf));
  if (i < 768) {
    if (i < 256) {
      float tc = fminf(fmaxf(ldsrc(a.src[4], i >> 5, bf), 1e-4f), 10.f);
      qscale[i] = tc * 1.4426950408889634f;
    } else qscale[i] = 1.0f;
  }
}

// ---------------------------------------------------------------------------
// QKV mega-kernel: GN1 finish -> normalize tile -> K=256 GEMM -> q/k/v
// native layouts (unchanged, proven).
// ---------------------------------------------------------------------------
__global__ __launch_bounds__(256) void qkv_fused_kernel(
    const float* __restrict__ x_f, const float* __restrict__ part1p,
    const float* __restrict__ g1, const float* __restrict__ be1,
    const unsigned short* __restrict__ W, const float* __restrict__ qscale,
    unsigned short* __restrict__ qn, unsigned short* __restrict__ kn,
    unsigned short* __restrict__ vs) {
  int t = threadIdx.x;
  int w = t >> 6, lane = t & 63, l16 = lane & 15, quad = lane >> 4;
  int p0 = blockIdx.x * 16;
  int b = p0 >> 12;
  __shared__ float red[32][8][2];
  __shared__ float sm[32], si[32];
  {
    int g = t >> 3, seg = t & 7;
    float s = 0.f, s2 = 0.f;
    const float* pp = part1p + ((size_t)(b * 32 + g) * 128 + seg * 16) * 2;
#pragma unroll
    for (int k = 0; k < 16; ++k) { s += pp[k * 2]; s2 += pp[k * 2 + 1]; }
    red[g][seg][0] = s; red[g][seg][1] = s2;
  }
  __syncthreads();
  if (t < 32) {
    float s = 0.f, s2 = 0.f;
#pragma unroll
    for (int k = 0; k < 8; ++k) { s += red[t][k][0]; s2 += red[t][k][1]; }
    float mean = s * (1.f / 32768.f);
    float var = s2 * (1.f / 32768.f) - mean * mean;
    sm[t] = mean; si[t] = rsqrtf(var + GEPS);
  }
  __syncthreads();
  __shared__ unsigned short Ys[16][264];
  {
    int p = t & 15, cg = t >> 4;
    int n = (p0 & 4095) + p;
    const float* src = x_f + ((size_t)b * NC + cg * 16) * NPIX + n;
    U16x8 lo, hi;
#pragma unroll
    for (int cc = 0; cc < 16; ++cc) {
      int c = cg * 16 + cc;
      int g = c >> 3;
      float gg = g1[c] * si[g];
      float vv = (src[(size_t)cc * NPIX] - sm[g]) * gg + be1[c];
      if (cc < 8) lo.us[cc] = tobf(vv); else hi.us[cc - 8] = tobf(vv);
    }
    *(uint4*)&Ys[p][cg * 16] = lo.u4;
    *(uint4*)&Ys[p][cg * 16 + 8] = hi.u4;
  }
  __syncthreads();
  int ob = blockIdx.y * 384 + w * 96;
  f32x4 acc[6] = {};
#pragma unroll
  for (int k0 = 0; k0 < 256; k0 += 32) {
    U16x8 bfr; bfr.u4 = *(const uint4*)&Ys[l16][k0 + quad * 8];
#pragma unroll
    for (int ot = 0; ot < 6; ++ot) {
      U16x8 af;
      af.u4 = *(const uint4*)(W + (size_t)(ob + ot * 16 + l16) * 256 + k0 + quad * 8);
      acc[ot] = __builtin_amdgcn_mfma_f32_16x16x32_bf16(af.v, bfr.v, acc[ot], 0, 0, 0);
    }
  }
  int n = (p0 & 4095) + l16;
#pragma unroll
  for (int ot = 0; ot < 6; ++ot) {
    int oc = ob + ot * 16 + quad * 4;
    float v[4];
#pragma unroll
    for (int r = 0; r < 4; ++r) v[r] = acc[ot][r] * qscale[oc + r];
    int sec = oc >> 8;
    int c = oc & 255;
    if (sec < 2) {
      int hh = c >> 5, d = c & 31;
      unsigned short* base = sec == 0 ? qn : kn;
      uint2 pk;
      pk.x = (unsigned)tobf(v[0]) | ((unsigned)tobf(v[1]) << 16);
      pk.y = (unsigned)tobf(v[2]) | ((unsigned)tobf(v[3]) << 16);
      *(uint2*)(base + ((size_t)(b * NHEAD + hh) * NPIX + n) * HD + d) = pk;
    } else {
#pragma unroll
      for (int r = 0; r < 4; ++r)
        vs[((size_t)(b * NC + c + r)) * NPIX + n] = tobf(v[r]);
    }
  }
}

// ---------------------------------------------------------------------------
// MFMA flash attention v14 (round-6 best): in-register P via permlane
// (zero bank conflicts) + 2-tile unroll for intra-wave ILP. Unchanged.
// ---------------------------------------------------------------------------
__global__ __launch_bounds__(512) void attn14_kernel(
    const unsigned short* __restrict__ qn, const unsigned short* __restrict__ kn,
    const unsigned short* __restrict__ vs, float* __restrict__ pO,
    float* __restrict__ pl) {
  // Bijective XCD-pinned decode: HW round-robins consecutive block ids over
  // the 8 XCDs (f&7). Streams s = (chunk,h,b); 4 streams per XCD.
  int f = blockIdx.x;                   // 0..1023
  int xcd = f & 7, slot = f >> 3;       // slot 0..127
  int s = xcd + ((slot >> 5) << 3);     // stream 0..31
  int iblk = slot & 31;
  int chunk = s & 1;
  int h = (s >> 1) & 7;
  int b = s >> 4;
  int i0 = iblk * 128;
  int jbase = chunk * JLEN;
  int bh = b * NHEAD + h;
  int t = threadIdx.x;
  int w = t >> 6, lane = t & 63, l16 = lane & 15, quad = lane >> 4;

  __shared__ unsigned short Kt[2][4096];   // [dbuf][tileA|tileB], swizzled
  __shared__ unsigned short Vt[2][4096];

  U16x8 qf;
  qf.u4 = *(const uint4*)(qn + ((size_t)bh * NPIX + i0 + w * 16 + l16) * HD + quad * 8);
  U16x8 ones;
#pragma unroll
  for (int j = 0; j < 8; ++j) ones.us[j] = 0x3F80;

  const unsigned short* gp;
  lds_u32* dstA[2];                      // half A dst, static-indexed (rule #20)
  lds_u32* dstB[2];                      // half B dst
  if (w < 4) {
    int kj = (w << 4) + (lane >> 2);
    int kg = (lane & 3) ^ ((kj >> 1) & 3);
    gp = kn + ((size_t)bh * NPIX + jbase + kj) * HD + kg * 8;
    dstA[0] = (lds_u32*)&Kt[0][w * 512];
    dstA[1] = (lds_u32*)&Kt[1][w * 512];
    dstB[0] = (lds_u32*)&Kt[0][2048 + w * 512];
    dstB[1] = (lds_u32*)&Kt[1][2048 + w * 512];
  } else {
    int vd = ((w - 4) << 3) + (lane >> 3);
    int vg = (lane & 7) ^ (vd & 7);
    gp = vs + ((size_t)(b * NC + h * HD + vd)) * NPIX + jbase + vg * 8;
    dstA[0] = (lds_u32*)&Vt[0][(w - 4) * 512];
    dstA[1] = (lds_u32*)&Vt[1][(w - 4) * 512];
    dstB[0] = (lds_u32*)&Vt[0][2048 + (w - 4) * 512];
    dstB[1] = (lds_u32*)&Vt[1][2048 + (w - 4) * 512];
  }
  int ghalf = (w < 4) ? 64 * HD : 64;    // elements between tile t and t+1
  int gstep = 2 * ghalf;                 // advance per super-iteration

  f32x4 o0 = {0.f, 0.f, 0.f, 0.f}, o1 = {0.f, 0.f, 0.f, 0.f};
  f32x4 lacc = {0.f, 0.f, 0.f, 0.f};
  const f32x4 zf = {0.f, 0.f, 0.f, 0.f};

  int sp = (quad ^ ((l16 >> 1) & 3)) * 8;

  // Prologue: DMA tiles 0,1 -> buf 0 (halves A,B).
  __builtin_amdgcn_global_load_lds((glb_u32*)gp, dstA[0], 16, 0, 0);
  __builtin_amdgcn_global_load_lds((glb_u32*)(gp + ghalf), dstB[0], 16, 0, 0);
  gp += gstep;

  // exp+permlane+PV for one tile (base = LDS offset of tile half).
#define SOFTPV(ST, BASE)                                                        \
  {                                                                             \
    unsigned X0 = packtrunc(__builtin_amdgcn_exp2f(ST[0][0]),                   \
                            __builtin_amdgcn_exp2f(ST[0][1]));                  \
    unsigned Y0 = packtrunc(__builtin_amdgcn_exp2f(ST[0][2]),                   \
                            __builtin_amdgcn_exp2f(ST[0][3]));                  \
    unsigned X1 = packtrunc(__builtin_amdgcn_exp2f(ST[1][0]),                   \
                            __builtin_amdgcn_exp2f(ST[1][1]));                  \
    unsigned Y1 = packtrunc(__builtin_amdgcn_exp2f(ST[1][2]),                   \
                            __builtin_amdgcn_exp2f(ST[1][3]));                  \
    unsigned X2 = packtrunc(__builtin_amdgcn_exp2f(ST[2][0]),                   \
                            __builtin_amdgcn_exp2f(ST[2][1]));                  \
    unsigned Y2 = packtrunc(__builtin_amdgcn_exp2f(ST[2][2]),                   \
                            __builtin_amdgcn_exp2f(ST[2][3]));                  \
    unsigned X3 = packtrunc(__builtin_amdgcn_exp2f(ST[3][0]),                   \
                            __builtin_amdgcn_exp2f(ST[3][1]));                  \
    unsigned Y3 = packtrunc(__builtin_amdgcn_exp2f(ST[3][2]),                   \
                            __builtin_amdgcn_exp2f(ST[3][3]));                  \
    plane32(X0, X1); plane16(X0, X1);                                           \
    plane32(Y0, Y1); plane16(Y0, Y1);                                           \
    plane32(X2, X3); plane16(X2, X3);                                           \
    plane32(Y2, Y3); plane16(Y2, Y3);                                           \
    __builtin_amdgcn_s_setprio(1);                                              \
    {                                                                           \
      U16x8 pb; pb.u32[0] = X0; pb.u32[1] = Y0; pb.u32[2] = X1; pb.u32[3] = Y1; \
      int vp = (quad ^ (l16 & 7)) * 8;                                          \
      U16x8 va; va.u4 = *(const uint4*)&(BASE)[l16 * 64 + vp];                  \
      U16x8 vb2; vb2.u4 = *(const uint4*)&(BASE)[(16 + l16) * 64 + vp];         \
      o0 = __builtin_amdgcn_mfma_f32_16x16x32_bf16(va.v, pb.v, o0, 0, 0, 0);    \
      o1 = __builtin_amdgcn_mfma_f32_16x16x32_bf16(vb2.v, pb.v, o1, 0, 0, 0);   \
      lacc = __builtin_amdgcn_mfma_f32_16x16x32_bf16(ones.v, pb.v, lacc, 0, 0, 0);\
    }                                                                           \
    {                                                                           \
      U16x8 pb; pb.u32[0] = X2; pb.u32[1] = Y2; pb.u32[2] = X3; pb.u32[3] = Y3; \
      int vp = ((4 + quad) ^ (l16 & 7)) * 8;                                    \
      U16x8 va; va.u4 = *(const uint4*)&(BASE)[l16 * 64 + vp];                  \
      U16x8 vb2; vb2.u4 = *(const uint4*)&(BASE)[(16 + l16) * 64 + vp];         \
      o0 = __builtin_amdgcn_mfma_f32_16x16x32_bf16(va.v, pb.v, o0, 0, 0, 0);    \
      o1 = __builtin_amdgcn_mfma_f32_16x16x32_bf16(vb2.v, pb.v, o1, 0, 0, 0);   \
      lacc = __builtin_amdgcn_mfma_f32_16x16x32_bf16(ones.v, pb.v, lacc, 0, 0, 0);\
    }                                                                           \
    __builtin_amdgcn_s_setprio(0);                                              \
  }

  // One super-iteration: tiles {2s,2s+1} from buf CUR; stage {2s+2,2s+3}.
#define ATTN_STEP(CUR, ISSUE)                                                   \
  {                                                                             \
    asm volatile("s_waitcnt vmcnt(0)" ::: "memory");                            \
    __builtin_amdgcn_s_barrier();                                               \
    if (ISSUE) {                                                                \
      __builtin_amdgcn_global_load_lds((glb_u32*)gp, dstA[(CUR) ^ 1], 16, 0, 0);\
      __builtin_amdgcn_global_load_lds((glb_u32*)(gp + ghalf), dstB[(CUR) ^ 1], \
                                       16, 0, 0);                               \
      gp += gstep;                                                              \
    }                                                                           \
    __builtin_amdgcn_sched_barrier(0);                                          \
    f32x4 stA[4], stB[4];                                                       \
    __builtin_amdgcn_s_setprio(1);                                              \
    _Pragma("unroll")                                                           \
    for (int jj = 0; jj < 4; ++jj) {                                            \
      U16x8 kf; kf.u4 = *(const uint4*)&Kt[CUR][(jj * 16 + l16) * 32 + sp];     \
      stA[jj] = __builtin_amdgcn_mfma_f32_16x16x32_bf16(kf.v, qf.v, zf, 0, 0, 0);\
    }                                                                           \
    _Pragma("unroll")                                                           \
    for (int jj = 0; jj < 4; ++jj) {                                            \
      U16x8 kf;                                                                 \
      kf.u4 = *(const uint4*)&Kt[CUR][2048 + (jj * 16 + l16) * 32 + sp];        \
      stB[jj] = __builtin_amdgcn_mfma_f32_16x16x32_bf16(kf.v, qf.v, zf, 0, 0, 0);\
    }                                                                           \
    __builtin_amdgcn_s_setprio(0);                                              \
    SOFTPV(stA, (&Vt[CUR][0]))                                                  \
    SOFTPV(stB, (&Vt[CUR][2048]))                                               \
  }

  // 32 tiles = 16 super-iterations: 14 rolled + 2 peeled (last stages none).
#pragma unroll 1
  for (int it = 0; it < 7; ++it) {
    ATTN_STEP(0, 1)
    ATTN_STEP(1, 1)
  }
  ATTN_STEP(0, 1)
  ATTN_STEP(1, 0)
#undef ATTN_STEP
#undef SOFTPV

  int pr = bh * 64 + iblk * 2 + (w >> 2);
  float* ob = pO + ((size_t)chunk * 1024 + pr) * 2048;
  int icol = (w & 3) * 16 + l16;
#pragma unroll
  for (int r = 0; r < 4; ++r) {
    ob[(quad * 4 + r) * 64 + icol] = o0[r];
    ob[(16 + quad * 4 + r) * 64 + icol] = o1[r];
  }
  if (quad == 0)
    pl[((size_t)chunk * 1024 + pr) * 64 + icol] = lacc[0];
}

// ---------------------------------------------------------------------------
// wout GEMM, r9: CHANNEL-SPLIT x2 (1024 blocks, 128 out-chans each) to lift
// occupancy from 2 -> 4 blocks/CU (grid was the binding constraint; LDS/VGPR
// allow 4+). pO/pl reads duplicate x2 (L3-resident); W/res/xres/part2p split
// cleanly. Same K-order and partial-sum order => bitwise-identical outputs.
// ---------------------------------------------------------------------------
__global__ __launch_bounds__(256) void wout_kernel(
    const unsigned short* __restrict__ W, const float* __restrict__ pO,
    const float* __restrict__ pl, const float* __restrict__ bias,
    const float* __restrict__ res, float* __restrict__ xres_t,
    float* __restrict__ part2p) {
  int t = threadIdx.x;
  int w = t >> 6, lane = t & 63, l16 = lane & 15, quad = lane >> 4;
  int half = blockIdx.x & 1, ptile = blockIdx.x >> 1;
  int p = ptile * 16 + l16;
  int b = p >> 12, n = p & 4095;
  int i = p & 63, iblk = (p >> 6) & 63;
  int ob = half * 128 + w * 32;          // wave covers 32 chans = 2 ot-tiles
  float rinv8[8];
#pragma unroll
  for (int hh = 0; hh < 8; ++hh) {
    size_t pr = (size_t)(b * NHEAD + hh) * 64 + iblk;
    float l = pl[pr * 64 + i] + pl[(1024 + pr) * 64 + i];
    rinv8[hh] = 1.f / l;
  }
  f32x4 acc[2] = {};
#pragma unroll
  for (int k0 = 0; k0 < 256; k0 += 32) {
    int hh = k0 >> 5;
    const float* q0 = pO + ((size_t)(b * NHEAD + hh) * 64 + iblk) * 2048 + quad * 8 * 64 + i;
    const float* q1 = q0 + (size_t)1024 * 2048;
    float rv = rinv8[hh];
    U16x8 bfr;
#pragma unroll
    for (int u = 0; u < 4; ++u) {
      float va = (q0[(2 * u) * 64] + q1[(2 * u) * 64]) * rv;
      float vb = (q0[(2 * u + 1) * 64] + q1[(2 * u + 1) * 64]) * rv;
      bfr.u32[u] = packtrunc(va, vb);
    }
#pragma unroll
    for (int ot = 0; ot < 2; ++ot) {
      U16x8 af;
      af.u4 = *(const uint4*)(W + (size_t)(ob + ot * 16 + l16) * 256 + k0 + quad * 8);
      acc[ot] = __builtin_amdgcn_mfma_f32_16x16x32_bf16(af.v, bfr.v, acc[ot], 0, 0, 0);
    }
  }
  __shared__ float sb[256][2][2];
#pragma unroll
  for (int ot = 0; ot < 2; ++ot) {
    int oc = ob + ot * 16 + quad * 4;
    float s = 0.f, s2 = 0.f;
    float v4[4];
#pragma unroll
    for (int r = 0; r < 4; ++r) {
      float vv = acc[ot][r] + bias[oc + r] + res[((size_t)(b * NC + oc + r)) * NPIX + n];
      v4[r] = vv;
      s += vv; s2 += vv * vv;
    }
    *(float4*)&xres_t[(size_t)p * NC + oc] = make_float4(v4[0], v4[1], v4[2], v4[3]);
    sb[t][ot][0] = s; sb[t][ot][1] = s2;
  }
  __syncthreads();
  if (t < 16) {  // local group lg == t; global group = half*16 + lg (8 chans)
    int ww = t >> 2, rem = t & 3, ot = rem >> 1, qp = rem & 1;
    float s = 0.f, s2 = 0.f;
#pragma unroll
    for (int q = 2 * qp; q < 2 * qp + 2; ++q)
      for (int l = 0; l < 16; ++l) {
        int tt = ww * 64 + q * 16 + l;
        s += sb[tt][ot][0]; s2 += sb[tt][ot][1];
      }
    size_t idx = ((size_t)(b * 32 + half * 16 + t) * 256 + (ptile & 255)) * 2;
    part2p[idx] = s; part2p[idx + 1] = s2;
  }
}

// ---------------------------------------------------------------------------
// MLP mega-kernel, r9: OUTPUT-SPLIT x2 (1024 blocks). Each block still does
// GN2 finish + normalize + W1/Hs (duplicated, cheap) but splits W2's 256
// outputs and the epilogue across the pair -> 4 blocks/CU occupancy. Same
// per-element math/order => bitwise-identical outputs.
// ---------------------------------------------------------------------------
__global__ __launch_bounds__(256) void mlp_fused_kernel(
    const void* __restrict__ xraw, const float* __restrict__ xres_t,
    const float* __restrict__ part2p, const float* __restrict__ g2,
    const float* __restrict__ be2, const unsigned short* __restrict__ W1,
    const float* __restrict__ b1, const unsigned short* __restrict__ W2,
    const float* __restrict__ b2, void* __restrict__ dout) {
  int wbf = detect_bf(xraw);
  int t = threadIdx.x;
  int w = t >> 6, lane = t & 63, l16 = lane & 15, quad = lane >> 4;
  int half = blockIdx.x & 1;
  int p0 = (blockIdx.x >> 1) * 16;
  int b = p0 >> 12;
  __shared__ float red[32][8][2];
  __shared__ float sm[32], si[32];
  {
    int g = t >> 3, seg = t & 7;
    float s = 0.f, s2 = 0.f;
    const float* pp = part2p + ((size_t)(b * 32 + g) * 256 + seg * 32) * 2;
#pragma unroll
    for (int k = 0; k < 32; ++k) { s += pp[k * 2]; s2 += pp[k * 2 + 1]; }
    red[g][seg][0] = s; red[g][seg][1] = s2;
  }
  __syncthreads();
  if (t < 32) {
    float s = 0.f, s2 = 0.f;
#pragma unroll
    for (int k = 0; k < 8; ++k) { s += red[t][k][0]; s2 += red[t][k][1]; }
    float mean = s * (1.f / 32768.f);
    float var = s2 * (1.f / 32768.f) - mean * mean;
    sm[t] = mean; si[t] = rsqrtf(var + GEPS);
  }
  __syncthreads();
  __shared__ float Xs[16][261];
  __shared__ unsigned short Ys[16][264];
  {
    int p = t >> 4, cg = t & 15;  // coalesced: 16 consecutive t span one row
    const float* src = xres_t + (size_t)(p0 + p) * NC + cg * 16;
    U16x8 lo, hi;
#pragma unroll
    for (int cc = 0; cc < 16; ++cc) {
      int c = cg * 16 + cc;
      int g = c >> 3;
      float v = src[cc];
      Xs[p][c] = v;
      float yv = (v - sm[g]) * (g2[c] * si[g]) + be2[c];
      if (cc < 8) lo.us[cc] = tobf(yv); else hi.us[cc - 8] = tobf(yv);
    }
    *(uint4*)&Ys[p][cg * 16] = lo.u4;
    *(uint4*)&Ys[p][cg * 16 + 8] = hi.u4;
  }
  __syncthreads();
  f32x4 a1 = {0.f, 0.f, 0.f, 0.f};
#pragma unroll
  for (int k0 = 0; k0 < 256; k0 += 32) {
    U16x8 bfr; bfr.u4 = *(const uint4*)&Ys[l16][k0 + quad * 8];
    U16x8 af;
    af.u4 = *(const uint4*)(W1 + (size_t)(w * 16 + l16) * 256 + k0 + quad * 8);
    a1 = __builtin_amdgcn_mfma_f32_16x16x32_bf16(af.v, bfr.v, a1, 0, 0, 0);
  }
  __shared__ unsigned short Hs[16][72];
  {
    int oc = w * 16 + quad * 4;
    float h0 = geluf(a1[0] + b1[oc]),     h1 = geluf(a1[1] + b1[oc + 1]);
    float h2 = geluf(a1[2] + b1[oc + 2]), h3 = geluf(a1[3] + b1[oc + 3]);
    uint2 pk;
    pk.x = (unsigned)tobf(h0) | ((unsigned)tobf(h1) << 16);
    pk.y = (unsigned)tobf(h2) | ((unsigned)tobf(h3) << 16);
    *(uint2*)&Hs[l16][oc] = pk;
  }
  __syncthreads();
  f32x4 a2[2] = {};
#pragma unroll
  for (int k0 = 0; k0 < 64; k0 += 32) {
    U16x8 bfr; bfr.u4 = *(const uint4*)&Hs[l16][k0 + quad * 8];
#pragma unroll
    for (int ot = 0; ot < 2; ++ot) {
      U16x8 af;
      af.u4 = *(const uint4*)(W2 + (size_t)(half * 128 + w * 32 + ot * 16 + l16) * 64 + k0 + quad * 8);
      a2[ot] = __builtin_amdgcn_mfma_f32_16x16x32_bf16(af.v, bfr.v, a2[ot], 0, 0, 0);
    }
  }
  int n = (p0 & 4095) + l16;
#pragma unroll
  for (int ot = 0; ot < 2; ++ot) {
    int oc = half * 128 + w * 32 + ot * 16 + quad * 4;
#pragma unroll
    for (int r = 0; r < 4; ++r) {
      float v = a2[ot][r] + b2[oc + r] + Xs[l16][oc + r];
      size_t oidx = ((size_t)(b * NC + oc + r)) * NPIX + n;
      if (wbf) ((__hip_bfloat16*)dout)[oidx] = __float2bfloat16(v);
      else ((float*)dout)[oidx] = v;
    }
  }
}

// ---------------------------------------------------------------------------
// Launch pipeline: 5 kernels.
// ---------------------------------------------------------------------------
extern "C" void kernel_launch(void* const* d_in, const int* in_sizes, int n_in,
                              void* d_out, int out_size, void* d_ws, size_t ws_size,
                              hipStream_t stream) {
  float* ws = (float*)d_ws;
  size_t off = 16;
  float* x_f    = ws + off; off += (size_t)NB * NC * NPIX;
  float* wqkv_f = ws + off; off += 768 * 256;
  float* wout_f = ws + off; off += 256 * 256;
  float* bout_f = ws + off; off += 256;
  float* temp_f = ws + off; off += 8;
  float* g1_f   = ws + off; off += 256;
  float* be1_f  = ws + off; off += 256;
  float* g2_f   = ws + off; off += 256;
  float* be2_f  = ws + off; off += 256;
  float* wm1_f  = ws + off; off += 64 * 256;
  float* bm1_f  = ws + off; off += 64;
  float* wm2_f  = ws + off; off += 256 * 64;
  float* bm2_f  = ws + off; off += 256;
  float* xres   = ws + off; off += (size_t)NB * NC * NPIX;  // pixel-major [8192][256]
  unsigned short* qn     = (unsigned short*)(ws + off); off += 1048576;  // [16][4096][32]
  unsigned short* kn     = (unsigned short*)(ws + off); off += 1048576;  // [16][4096][32]
  unsigned short* vs     = (unsigned short*)(ws + off); off += 1048576;  // [2][256][4096]
  unsigned short* wqkv_b = (unsigned short*)(ws + off); off += 98304;
  unsigned short* wout_b = (unsigned short*)(ws + off); off += 32768;
  unsigned short* wm1_b  = (unsigned short*)(ws + off); off += 8192;
  unsigned short* wm2_b  = (unsigned short*)(ws + off); off += 8192;
  float* qscale = ws + off; off += 768;
  float* part1p = ws + off; off += 16384;   // [8192][2] GN1 block partials
  float* part2p = ws + off; off += 65536;   // [64 bg][256 blk][2] GN2 partials
  float* pO     = ws + off; off += (size_t)NCHUNK * 1024 * 2048;
  float* plb    = ws + off; off += (size_t)NCHUNK * 1024 * 64;
  (void)wqkv_f; (void)wout_f; (void)wm1_f; (void)wm2_f; (void)temp_f; (void)bm1_f;

  ConvArgs ca;
  int acc = 0;
  for (int i = 0; i < 13; ++i) {
    ca.src[i] = d_in[i];
    ca.off[i] = acc;
    acc += (i < n_in) ? in_sizes[i] : 0;
  }
  ca.off[13] = acc;
  conv_prep_kernel<<<(acc + 255) / 256, 256, 0, stream>>>(
      ca, x_f, acc, wqkv_b, wout_b, wm1_b, wm2_b, qscale, part1p);

  qkv_fused_kernel<<<dim3(512, 2), 256, 0, stream>>>(
      x_f, part1p, g1_f, be1_f, wqkv_b, qscale, qn, kn, vs);

  attn14_kernel<<<dim3(1024), 512, 0, stream>>>(qn, kn, vs, pO, plb);

  wout_kernel<<<1024, 256, 0, stream>>>(wout_b, pO, plb, bout_f, x_f, xres, part2p);

  mlp_fused_kernel<<<1024, 256, 0, stream>>>(
      d_in[0], xres, part2p, g2_f, be2_f, wm1_b, bm1_f, wm2_b, bm2_f, d_out);
}

// Round 11
// 205.807 us; speedup vs baseline: 1.0525x; 1.0525x over previous
//
#include <hip/hip_runtime.h>
#include <hip/hip_bf16.h>
#include <math.h>

// Problem constants (B=2, C=256, H=W=64, heads=8, hd=32, groups=32, hid=64)
#define NB 2
#define NC 256
#define NHEAD 8
#define HD 32
#define NPIX 4096
#define GEPS 1e-5f
#define NCHUNK 2          // j-split factor for attention (linear softmax => exact)
#define JLEN (NPIX / NCHUNK)

typedef short bf16x8 __attribute__((ext_vector_type(8)));
typedef float f32x4 __attribute__((ext_vector_type(4)));

typedef __attribute__((address_space(3))) unsigned int lds_u32;
typedef __attribute__((address_space(1))) const unsigned int glb_u32;

union U16x8 { uint4 u4; uint2 u2[2]; unsigned u32[4]; unsigned short us[8]; bf16x8 v; };

__device__ inline unsigned short tobf(float f) {  // round-to-nearest-even
  union { float f; unsigned u; } c; c.f = f;
  return (unsigned short)((c.u + 0x7FFFu + ((c.u >> 16) & 1u)) >> 16);
}
__device__ inline unsigned packtrunc(float lo, float hi) {  // truncating bf16 pack, 1 instr
  return __builtin_amdgcn_perm(__float_as_uint(hi), __float_as_uint(lo), 0x07060302u);
}
__device__ inline float geluf(float v) {
  return 0.5f * v * (1.f + erff(v * 0.70710678118654752f));
}
// gfx950 cross-lane swaps (MFMA-fragment redistribution primitives):
// P32: swap a[i+32]<->b[i]; P16: swap a[i+16]<->b[i] per 32-half.
__device__ inline void plane32(unsigned &a, unsigned &b) {
  asm("v_permlane32_swap_b32 %0, %1" : "+v"(a), "+v"(b));
}
__device__ inline void plane16(unsigned &a, unsigned &b) {
  asm("v_permlane16_swap_b32 %0, %1" : "+v"(a), "+v"(b));
}

// Per-block dtype self-detection (bf16 vs fp32 x): wave-0 ballot + broadcast.
__device__ inline int detect_bf(const void* xraw) {
  __shared__ int flg;
  int t = threadIdx.x;
  if (t < 64) {
    unsigned short h = ((const unsigned short*)xraw)[2 * t];
    unsigned e = (h >> 7) & 0xFFu;
    int weird = (e < 113u || e > 140u) ? 1 : 0;
    unsigned long long m = __ballot(weird);
    if (t == 0) flg = (__popcll(m) > 16) ? 0 : 1;
  }
  __syncthreads();
  return flg;
}

struct ConvArgs { const void* src[13]; int off[14]; };

__device__ inline float ldsrc(const void* p, int idx, int bf) {
  if (bf) {
    unsigned v = ((const unsigned short*)p)[idx];
    return __uint_as_float(v << 16);
  }
  return ((const float*)p)[idx];
}

// ---------------------------------------------------------------------------
// Fused convert + prep + GN1 block-partials (shfl reduction, r7).
// ---------------------------------------------------------------------------
__global__ __launch_bounds__(256) void conv_prep_kernel(
    ConvArgs a, float* __restrict__ dstbase, int total,
    unsigned short* __restrict__ wqkv_b, unsigned short* __restrict__ wout_b,
    unsigned short* __restrict__ wm1_b, unsigned short* __restrict__ wm2_b,
    float* __restrict__ qscale, float* __restrict__ part1p) {
  int bf = detect_bf(a.src[0]);
  int blk = blockIdx.x, t = threadIdx.x;
  int i = blk * 256 + t;
  float val = 0.f;
  if (i < total) {
    int s = 0;
    while (i >= a.off[s + 1]) ++s;
    val = ldsrc(a.src[s], i - a.off[s], bf);
    dstbase[i] = val;
  }
  // GN1 partials (x = segment 0, exactly blocks 0..8191)
  if (blk < 8192) {
    float s = val, s2 = val * val;
#pragma unroll
    for (int o = 32; o > 0; o >>= 1) {
      s += __shfl_down(s, o, 64);
      s2 += __shfl_down(s2, o, 64);
    }
    __shared__ float r4[4][2];
    if ((t & 63) == 0) { r4[t >> 6][0] = s; r4[t >> 6][1] = s2; }
    __syncthreads();
    if (t == 0) {
      part1p[blk * 2] = r4[0][0] + r4[1][0] + r4[2][0] + r4[3][0];
      part1p[blk * 2 + 1] = r4[0][1] + r4[1][1] + r4[2][1] + r4[3][1];
    }
  }
  // prep (reads raw sources)
  if (i < 196608) wqkv_b[i] = tobf(ldsrc(a.src[1], i, bf));
  else if (i < 262144) wout_b[i - 196608] = tobf(ldsrc(a.src[2], i - 196608, bf));
  else if (i < 278528) wm1_b[i - 262144] = tobf(ldsrc(a.src[9], i - 262144, bf));
  else if (i < 294912) wm2_b[i - 278528] = tobf(ldsrc(a.src[11], i - 278528, bf));
  if (i < 768) {
    if (i < 256) {
      float tc = fminf(fmaxf(ldsrc(a.src[4], i >> 5, bf), 1e-4f), 10.f);
      qscale[i] = tc * 1.4426950408889634f;
    } else qscale[i] = 1.0f;
  }
}

// ---------------------------------------------------------------------------
// QKV mega-kernel: GN1 finish -> normalize tile -> K=256 GEMM -> q/k/v
// native layouts (unchanged, proven).
// ---------------------------------------------------------------------------
__global__ __launch_bounds__(256) void qkv_fused_kernel(
    const float* __restrict__ x_f, const float* __restrict__ part1p,
    const float* __restrict__ g1, const float* __restrict__ be1,
    const unsigned short* __restrict__ W, const float* __restrict__ qscale,
    unsigned short* __restrict__ qn, unsigned short* __restrict__ kn,
    unsigned short* __restrict__ vs) {
  int t = threadIdx.x;
  int w = t >> 6, lane = t & 63, l16 = lane & 15, quad = lane >> 4;
  int p0 = blockIdx.x * 16;
  int b = p0 >> 12;
  __shared__ float red[32][8][2];
  __shared__ float sm[32], si[32];
  {
    int g = t >> 3, seg = t & 7;
    float s = 0.f, s2 = 0.f;
    const float* pp = part1p + ((size_t)(b * 32 + g) * 128 + seg * 16) * 2;
#pragma unroll
    for (int k = 0; k < 16; ++k) { s += pp[k * 2]; s2 += pp[k * 2 + 1]; }
    red[g][seg][0] = s; red[g][seg][1] = s2;
  }
  __syncthreads();
  if (t < 32) {
    float s = 0.f, s2 = 0.f;
#pragma unroll
    for (int k = 0; k < 8; ++k) { s += red[t][k][0]; s2 += red[t][k][1]; }
    float mean = s * (1.f / 32768.f);
    float var = s2 * (1.f / 32768.f) - mean * mean;
    sm[t] = mean; si[t] = rsqrtf(var + GEPS);
  }
  __syncthreads();
  __shared__ unsigned short Ys[16][264];
  {
    int p = t & 15, cg = t >> 4;
    int n = (p0 & 4095) + p;
    const float* src = x_f + ((size_t)b * NC + cg * 16) * NPIX + n;
    U16x8 lo, hi;
#pragma unroll
    for (int cc = 0; cc < 16; ++cc) {
      int c = cg * 16 + cc;
      int g = c >> 3;
      float gg = g1[c] * si[g];
      float vv = (src[(size_t)cc * NPIX] - sm[g]) * gg + be1[c];
      if (cc < 8) lo.us[cc] = tobf(vv); else hi.us[cc - 8] = tobf(vv);
    }
    *(uint4*)&Ys[p][cg * 16] = lo.u4;
    *(uint4*)&Ys[p][cg * 16 + 8] = hi.u4;
  }
  __syncthreads();
  int ob = blockIdx.y * 384 + w * 96;
  f32x4 acc[6] = {};
#pragma unroll
  for (int k0 = 0; k0 < 256; k0 += 32) {
    U16x8 bfr; bfr.u4 = *(const uint4*)&Ys[l16][k0 + quad * 8];
#pragma unroll
    for (int ot = 0; ot < 6; ++ot) {
      U16x8 af;
      af.u4 = *(const uint4*)(W + (size_t)(ob + ot * 16 + l16) * 256 + k0 + quad * 8);
      acc[ot] = __builtin_amdgcn_mfma_f32_16x16x32_bf16(af.v, bfr.v, acc[ot], 0, 0, 0);
    }
  }
  int n = (p0 & 4095) + l16;
#pragma unroll
  for (int ot = 0; ot < 6; ++ot) {
    int oc = ob + ot * 16 + quad * 4;
    float v[4];
#pragma unroll
    for (int r = 0; r < 4; ++r) v[r] = acc[ot][r] * qscale[oc + r];
    int sec = oc >> 8;
    int c = oc & 255;
    if (sec < 2) {
      int hh = c >> 5, d = c & 31;
      unsigned short* base = sec == 0 ? qn : kn;
      uint2 pk;
      pk.x = (unsigned)tobf(v[0]) | ((unsigned)tobf(v[1]) << 16);
      pk.y = (unsigned)tobf(v[2]) | ((unsigned)tobf(v[3]) << 16);
      *(uint2*)(base + ((size_t)(b * NHEAD + hh) * NPIX + n) * HD + d) = pk;
    } else {
#pragma unroll
      for (int r = 0; r < 4; ++r)
        vs[((size_t)(b * NC + c + r)) * NPIX + n] = tobf(v[r]);
    }
  }
}

// ---------------------------------------------------------------------------
// MFMA flash attention v14 (round-6 best): in-register P via permlane
// (zero bank conflicts) + 2-tile unroll for intra-wave ILP. Unchanged.
// ---------------------------------------------------------------------------
__global__ __launch_bounds__(512) void attn14_kernel(
    const unsigned short* __restrict__ qn, const unsigned short* __restrict__ kn,
    const unsigned short* __restrict__ vs, float* __restrict__ pO,
    float* __restrict__ pl) {
  // Bijective XCD-pinned decode: HW round-robins consecutive block ids over
  // the 8 XCDs (f&7). Streams s = (chunk,h,b); 4 streams per XCD.
  int f = blockIdx.x;                   // 0..1023
  int xcd = f & 7, slot = f >> 3;       // slot 0..127
  int s = xcd + ((slot >> 5) << 3);     // stream 0..31
  int iblk = slot & 31;
  int chunk = s & 1;
  int h = (s >> 1) & 7;
  int b = s >> 4;
  int i0 = iblk * 128;
  int jbase = chunk * JLEN;
  int bh = b * NHEAD + h;
  int t = threadIdx.x;
  int w = t >> 6, lane = t & 63, l16 = lane & 15, quad = lane >> 4;

  __shared__ unsigned short Kt[2][4096];   // [dbuf][tileA|tileB], swizzled
  __shared__ unsigned short Vt[2][4096];

  U16x8 qf;
  qf.u4 = *(const uint4*)(qn + ((size_t)bh * NPIX + i0 + w * 16 + l16) * HD + quad * 8);
  U16x8 ones;
#pragma unroll
  for (int j = 0; j < 8; ++j) ones.us[j] = 0x3F80;

  const unsigned short* gp;
  lds_u32* dstA[2];                      // half A dst, static-indexed (rule #20)
  lds_u32* dstB[2];                      // half B dst
  if (w < 4) {
    int kj = (w << 4) + (lane >> 2);
    int kg = (lane & 3) ^ ((kj >> 1) & 3);
    gp = kn + ((size_t)bh * NPIX + jbase + kj) * HD + kg * 8;
    dstA[0] = (lds_u32*)&Kt[0][w * 512];
    dstA[1] = (lds_u32*)&Kt[1][w * 512];
    dstB[0] = (lds_u32*)&Kt[0][2048 + w * 512];
    dstB[1] = (lds_u32*)&Kt[1][2048 + w * 512];
  } else {
    int vd = ((w - 4) << 3) + (lane >> 3);
    int vg = (lane & 7) ^ (vd & 7);
    gp = vs + ((size_t)(b * NC + h * HD + vd)) * NPIX + jbase + vg * 8;
    dstA[0] = (lds_u32*)&Vt[0][(w - 4) * 512];
    dstA[1] = (lds_u32*)&Vt[1][(w - 4) * 512];
    dstB[0] = (lds_u32*)&Vt[0][2048 + (w - 4) * 512];
    dstB[1] = (lds_u32*)&Vt[1][2048 + (w - 4) * 512];
  }
  int ghalf = (w < 4) ? 64 * HD : 64;    // elements between tile t and t+1
  int gstep = 2 * ghalf;                 // advance per super-iteration

  f32x4 o0 = {0.f, 0.f, 0.f, 0.f}, o1 = {0.f, 0.f, 0.f, 0.f};
  f32x4 lacc = {0.f, 0.f, 0.f, 0.f};
  const f32x4 zf = {0.f, 0.f, 0.f, 0.f};

  int sp = (quad ^ ((l16 >> 1) & 3)) * 8;

  // Prologue: DMA tiles 0,1 -> buf 0 (halves A,B).
  __builtin_amdgcn_global_load_lds((glb_u32*)gp, dstA[0], 16, 0, 0);
  __builtin_amdgcn_global_load_lds((glb_u32*)(gp + ghalf), dstB[0], 16, 0, 0);
  gp += gstep;

  // exp+permlane+PV for one tile (base = LDS offset of tile half).
#define SOFTPV(ST, BASE)                                                        \
  {                                                                             \
    unsigned X0 = packtrunc(__builtin_amdgcn_exp2f(ST[0][0]),                   \
                            __builtin_amdgcn_exp2f(ST[0][1]));                  \
    unsigned Y0 = packtrunc(__builtin_amdgcn_exp2f(ST[0][2]),                   \
                            __builtin_amdgcn_exp2f(ST[0][3]));                  \
    unsigned X1 = packtrunc(__builtin_amdgcn_exp2f(ST[1][0]),                   \
                            __builtin_amdgcn_exp2f(ST[1][1]));                  \
    unsigned Y1 = packtrunc(__builtin_amdgcn_exp2f(ST[1][2]),                   \
                            __builtin_amdgcn_exp2f(ST[1][3]));                  \
    unsigned X2 = packtrunc(__builtin_amdgcn_exp2f(ST[2][0]),                   \
                            __builtin_amdgcn_exp2f(ST[2][1]));                  \
    unsigned Y2 = packtrunc(__builtin_amdgcn_exp2f(ST[2][2]),                   \
                            __builtin_amdgcn_exp2f(ST[2][3]));                  \
    unsigned X3 = packtrunc(__builtin_amdgcn_exp2f(ST[3][0]),                   \
                            __builtin_amdgcn_exp2f(ST[3][1]));                  \
    unsigned Y3 = packtrunc(__builtin_amdgcn_exp2f(ST[3][2]),                   \
                            __builtin_amdgcn_exp2f(ST[3][3]));                  \
    plane32(X0, X1); plane16(X0, X1);                                           \
    plane32(Y0, Y1); plane16(Y0, Y1);                                           \
    plane32(X2, X3); plane16(X2, X3);                                           \
    plane32(Y2, Y3); plane16(Y2, Y3);                                           \
    __builtin_amdgcn_s_setprio(1);                                              \
    {                                                                           \
      U16x8 pb; pb.u32[0] = X0; pb.u32[1] = Y0; pb.u32[2] = X1; pb.u32[3] = Y1; \
      int vp = (quad ^ (l16 & 7)) * 8;                                          \
      U16x8 va; va.u4 = *(const uint4*)&(BASE)[l16 * 64 + vp];                  \
      U16x8 vb2; vb2.u4 = *(const uint4*)&(BASE)[(16 + l16) * 64 + vp];         \
      o0 = __builtin_amdgcn_mfma_f32_16x16x32_bf16(va.v, pb.v, o0, 0, 0, 0);    \
      o1 = __builtin_amdgcn_mfma_f32_16x16x32_bf16(vb2.v, pb.v, o1, 0, 0, 0);   \
      lacc = __builtin_amdgcn_mfma_f32_16x16x32_bf16(ones.v, pb.v, lacc, 0, 0, 0);\
    }                                                                           \
    {                                                                           \
      U16x8 pb; pb.u32[0] = X2; pb.u32[1] = Y2; pb.u32[2] = X3; pb.u32[3] = Y3; \
      int vp = ((4 + quad) ^ (l16 & 7)) * 8;                                    \
      U16x8 va; va.u4 = *(const uint4*)&(BASE)[l16 * 64 + vp];                  \
      U16x8 vb2; vb2.u4 = *(const uint4*)&(BASE)[(16 + l16) * 64 + vp];         \
      o0 = __builtin_amdgcn_mfma_f32_16x16x32_bf16(va.v, pb.v, o0, 0, 0, 0);    \
      o1 = __builtin_amdgcn_mfma_f32_16x16x32_bf16(vb2.v, pb.v, o1, 0, 0, 0);   \
      lacc = __builtin_amdgcn_mfma_f32_16x16x32_bf16(ones.v, pb.v, lacc, 0, 0, 0);\
    }                                                                           \
    __builtin_amdgcn_s_setprio(0);                                              \
  }

  // One super-iteration: tiles {2s,2s+1} from buf CUR; stage {2s+2,2s+3}.
#define ATTN_STEP(CUR, ISSUE)                                                   \
  {                                                                             \
    asm volatile("s_waitcnt vmcnt(0)" ::: "memory");                            \
    __builtin_amdgcn_s_barrier();                                               \
    if (ISSUE) {                                                                \
      __builtin_amdgcn_global_load_lds((glb_u32*)gp, dstA[(CUR) ^ 1], 16, 0, 0);\
      __builtin_amdgcn_global_load_lds((glb_u32*)(gp + ghalf), dstB[(CUR) ^ 1], \
                                       16, 0, 0);                               \
      gp += gstep;                                                              \
    }                                                                           \
    __builtin_amdgcn_sched_barrier(0);                                          \
    f32x4 stA[4], stB[4];                                                       \
    __builtin_amdgcn_s_setprio(1);                                              \
    _Pragma("unroll")                                                           \
    for (int jj = 0; jj < 4; ++jj) {                                            \
      U16x8 kf; kf.u4 = *(const uint4*)&Kt[CUR][(jj * 16 + l16) * 32 + sp];     \
      stA[jj] = __builtin_amdgcn_mfma_f32_16x16x32_bf16(kf.v, qf.v, zf, 0, 0, 0);\
    }                                                                           \
    _Pragma("unroll")                                                           \
    for (int jj = 0; jj < 4; ++jj) {                                            \
      U16x8 kf;                                                                 \
      kf.u4 = *(const uint4*)&Kt[CUR][2048 + (jj * 16 + l16) * 32 + sp];        \
      stB[jj] = __builtin_amdgcn_mfma_f32_16x16x32_bf16(kf.v, qf.v, zf, 0, 0, 0);\
    }                                                                           \
    __builtin_amdgcn_s_setprio(0);                                              \
    SOFTPV(stA, (&Vt[CUR][0]))                                                  \
    SOFTPV(stB, (&Vt[CUR][2048]))                                               \
  }

  // 32 tiles = 16 super-iterations: 14 rolled + 2 peeled (last stages none).
#pragma unroll 1
  for (int it = 0; it < 7; ++it) {
    ATTN_STEP(0, 1)
    ATTN_STEP(1, 1)
  }
  ATTN_STEP(0, 1)
  ATTN_STEP(1, 0)
#undef ATTN_STEP
#undef SOFTPV

  int pr = bh * 64 + iblk * 2 + (w >> 2);
  float* ob = pO + ((size_t)chunk * 1024 + pr) * 2048;
  int icol = (w & 3) * 16 + l16;
#pragma unroll
  for (int r = 0; r < 4; ++r) {
    ob[(quad * 4 + r) * 64 + icol] = o0[r];
    ob[(16 + quad * 4 + r) * 64 + icol] = o1[r];
  }
  if (quad == 0)
    pl[((size_t)chunk * 1024 + pr) * 64 + icol] = lacc[0];
}

// ---------------------------------------------------------------------------
// wout GEMM with INLINE combine (round-9 proven config: 512 blocks, full 256
// out-chans per block). r10's channel-split x2 regressed: pO reads doubled
// (16.8->33.6 MB L3) and the occupancy gain didn't pay for it.
// ---------------------------------------------------------------------------
__global__ __launch_bounds__(256) void wout_kernel(
    const unsigned short* __restrict__ W, const float* __restrict__ pO,
    const float* __restrict__ pl, const float* __restrict__ bias,
    const float* __restrict__ res, float* __restrict__ xres_t,
    float* __restrict__ part2p) {
  int t = threadIdx.x;
  int w = t >> 6, lane = t & 63, l16 = lane & 15, quad = lane >> 4;
  int p = blockIdx.x * 16 + l16;
  int b = p >> 12, n = p & 4095;
  int i = p & 63, iblk = (p >> 6) & 63;
  int ob = w * 64;
  float rinv8[8];
#pragma unroll
  for (int hh = 0; hh < 8; ++hh) {
    size_t pr = (size_t)(b * NHEAD + hh) * 64 + iblk;
    float l = pl[pr * 64 + i] + pl[(1024 + pr) * 64 + i];
    rinv8[hh] = 1.f / l;
  }
  f32x4 acc[4] = {};
#pragma unroll
  for (int k0 = 0; k0 < 256; k0 += 32) {
    int hh = k0 >> 5;
    const float* q0 = pO + ((size_t)(b * NHEAD + hh) * 64 + iblk) * 2048 + quad * 8 * 64 + i;
    const float* q1 = q0 + (size_t)1024 * 2048;
    float rv = rinv8[hh];
    U16x8 bfr;
#pragma unroll
    for (int u = 0; u < 4; ++u) {
      float va = (q0[(2 * u) * 64] + q1[(2 * u) * 64]) * rv;
      float vb = (q0[(2 * u + 1) * 64] + q1[(2 * u + 1) * 64]) * rv;
      bfr.u32[u] = packtrunc(va, vb);
    }
#pragma unroll
    for (int ot = 0; ot < 4; ++ot) {
      U16x8 af;
      af.u4 = *(const uint4*)(W + (size_t)(ob + ot * 16 + l16) * 256 + k0 + quad * 8);
      acc[ot] = __builtin_amdgcn_mfma_f32_16x16x32_bf16(af.v, bfr.v, acc[ot], 0, 0, 0);
    }
  }
  __shared__ float sb[256][4][2];
#pragma unroll
  for (int ot = 0; ot < 4; ++ot) {
    int oc = ob + ot * 16 + quad * 4;
    float s = 0.f, s2 = 0.f;
    float v4[4];
#pragma unroll
    for (int r = 0; r < 4; ++r) {
      float vv = acc[ot][r] + bias[oc + r] + res[((size_t)(b * NC + oc + r)) * NPIX + n];
      v4[r] = vv;
      s += vv; s2 += vv * vv;
    }
    *(float4*)&xres_t[(size_t)p * NC + oc] = make_float4(v4[0], v4[1], v4[2], v4[3]);
    sb[t][ot][0] = s; sb[t][ot][1] = s2;
  }
  __syncthreads();
  if (t < 32) {  // group g == t; channels [g*8, g*8+8)
    int ww = t >> 3, rem = t & 7, ot = rem >> 1, qp = rem & 1;
    float s = 0.f, s2 = 0.f;
#pragma unroll
    for (int q = 2 * qp; q < 2 * qp + 2; ++q)
      for (int l = 0; l < 16; ++l) {
        int tt = ww * 64 + q * 16 + l;
        s += sb[tt][ot][0]; s2 += sb[tt][ot][1];
      }
    size_t idx = ((size_t)(b * 32 + t) * 256 + (blockIdx.x & 255)) * 2;
    part2p[idx] = s; part2p[idx + 1] = s2;
  }
}

// ---------------------------------------------------------------------------
// MLP mega-kernel (round-9 proven config: 512 blocks, full outputs). r10's
// output-split x2 regressed: GN2+normalize+W1 duplicated per half.
// ---------------------------------------------------------------------------
__global__ __launch_bounds__(256) void mlp_fused_kernel(
    const void* __restrict__ xraw, const float* __restrict__ xres_t,
    const float* __restrict__ part2p, const float* __restrict__ g2,
    const float* __restrict__ be2, const unsigned short* __restrict__ W1,
    const float* __restrict__ b1, const unsigned short* __restrict__ W2,
    const float* __restrict__ b2, void* __restrict__ dout) {
  int wbf = detect_bf(xraw);
  int t = threadIdx.x;
  int w = t >> 6, lane = t & 63, l16 = lane & 15, quad = lane >> 4;
  int p0 = blockIdx.x * 16;
  int b = p0 >> 12;
  __shared__ float red[32][8][2];
  __shared__ float sm[32], si[32];
  {
    int g = t >> 3, seg = t & 7;
    float s = 0.f, s2 = 0.f;
    const float* pp = part2p + ((size_t)(b * 32 + g) * 256 + seg * 32) * 2;
#pragma unroll
    for (int k = 0; k < 32; ++k) { s += pp[k * 2]; s2 += pp[k * 2 + 1]; }
    red[g][seg][0] = s; red[g][seg][1] = s2;
  }
  __syncthreads();
  if (t < 32) {
    float s = 0.f, s2 = 0.f;
#pragma unroll
    for (int k = 0; k < 8; ++k) { s += red[t][k][0]; s2 += red[t][k][1]; }
    float mean = s * (1.f / 32768.f);
    float var = s2 * (1.f / 32768.f) - mean * mean;
    sm[t] = mean; si[t] = rsqrtf(var + GEPS);
  }
  __syncthreads();
  __shared__ float Xs[16][261];
  __shared__ unsigned short Ys[16][264];
  {
    int p = t >> 4, cg = t & 15;  // coalesced: 16 consecutive t span one row
    const float* src = xres_t + (size_t)(p0 + p) * NC + cg * 16;
    U16x8 lo, hi;
#pragma unroll
    for (int cc = 0; cc < 16; ++cc) {
      int c = cg * 16 + cc;
      int g = c >> 3;
      float v = src[cc];
      Xs[p][c] = v;
      float yv = (v - sm[g]) * (g2[c] * si[g]) + be2[c];
      if (cc < 8) lo.us[cc] = tobf(yv); else hi.us[cc - 8] = tobf(yv);
    }
    *(uint4*)&Ys[p][cg * 16] = lo.u4;
    *(uint4*)&Ys[p][cg * 16 + 8] = hi.u4;
  }
  __syncthreads();
  f32x4 a1 = {0.f, 0.f, 0.f, 0.f};
#pragma unroll
  for (int k0 = 0; k0 < 256; k0 += 32) {
    U16x8 bfr; bfr.u4 = *(const uint4*)&Ys[l16][k0 + quad * 8];
    U16x8 af;
    af.u4 = *(const uint4*)(W1 + (size_t)(w * 16 + l16) * 256 + k0 + quad * 8);
    a1 = __builtin_amdgcn_mfma_f32_16x16x32_bf16(af.v, bfr.v, a1, 0, 0, 0);
  }
  __shared__ unsigned short Hs[16][72];
  {
    int oc = w * 16 + quad * 4;
    float h0 = geluf(a1[0] + b1[oc]),     h1 = geluf(a1[1] + b1[oc + 1]);
    float h2 = geluf(a1[2] + b1[oc + 2]), h3 = geluf(a1[3] + b1[oc + 3]);
    uint2 pk;
    pk.x = (unsigned)tobf(h0) | ((unsigned)tobf(h1) << 16);
    pk.y = (unsigned)tobf(h2) | ((unsigned)tobf(h3) << 16);
    *(uint2*)&Hs[l16][oc] = pk;
  }
  __syncthreads();
  f32x4 a2[4] = {};
#pragma unroll
  for (int k0 = 0; k0 < 64; k0 += 32) {
    U16x8 bfr; bfr.u4 = *(const uint4*)&Hs[l16][k0 + quad * 8];
#pragma unroll
    for (int ot = 0; ot < 4; ++ot) {
      U16x8 af;
      af.u4 = *(const uint4*)(W2 + (size_t)(w * 64 + ot * 16 + l16) * 64 + k0 + quad * 8);
      a2[ot] = __builtin_amdgcn_mfma_f32_16x16x32_bf16(af.v, bfr.v, a2[ot], 0, 0, 0);
    }
  }
  int n = (p0 & 4095) + l16;
#pragma unroll
  for (int ot = 0; ot < 4; ++ot) {
    int oc = w * 64 + ot * 16 + quad * 4;
#pragma unroll
    for (int r = 0; r < 4; ++r) {
      float v = a2[ot][r] + b2[oc + r] + Xs[l16][oc + r];
      size_t oidx = ((size_t)(b * NC + oc + r)) * NPIX + n;
      if (wbf) ((__hip_bfloat16*)dout)[oidx] = __float2bfloat16(v);
      else ((float*)dout)[oidx] = v;
    }
  }
}

// ---------------------------------------------------------------------------
// Launch pipeline: 5 kernels (round-9 proven grids).
// ---------------------------------------------------------------------------
extern "C" void kernel_launch(void* const* d_in, const int* in_sizes, int n_in,
                              void* d_out, int out_size, void* d_ws, size_t ws_size,
                              hipStream_t stream) {
  float* ws = (float*)d_ws;
  size_t off = 16;
  float* x_f    = ws + off; off += (size_t)NB * NC * NPIX;
  float* wqkv_f = ws + off; off += 768 * 256;
  float* wout_f = ws + off; off += 256 * 256;
  float* bout_f = ws + off; off += 256;
  float* temp_f = ws + off; off += 8;
  float* g1_f   = ws + off; off += 256;
  float* be1_f  = ws + off; off += 256;
  float* g2_f   = ws + off; off += 256;
  float* be2_f  = ws + off; off += 256;
  float* wm1_f  = ws + off; off += 64 * 256;
  float* bm1_f  = ws + off; off += 64;
  float* wm2_f  = ws + off; off += 256 * 64;
  float* bm2_f  = ws + off; off += 256;
  float* xres   = ws + off; off += (size_t)NB * NC * NPIX;  // pixel-major [8192][256]
  unsigned short* qn     = (unsigned short*)(ws + off); off += 1048576;  // [16][4096][32]
  unsigned short* kn     = (unsigned short*)(ws + off); off += 1048576;  // [16][4096][32]
  unsigned short* vs     = (unsigned short*)(ws + off); off += 1048576;  // [2][256][4096]
  unsigned short* wqkv_b = (unsigned short*)(ws + off); off += 98304;
  unsigned short* wout_b = (unsigned short*)(ws + off); off += 32768;
  unsigned short* wm1_b  = (unsigned short*)(ws + off); off += 8192;
  unsigned short* wm2_b  = (unsigned short*)(ws + off); off += 8192;
  float* qscale = ws + off; off += 768;
  float* part1p = ws + off; off += 16384;   // [8192][2] GN1 block partials
  float* part2p = ws + off; off += 65536;   // [64 bg][256 blk][2] GN2 partials
  float* pO     = ws + off; off += (size_t)NCHUNK * 1024 * 2048;
  float* plb    = ws + off; off += (size_t)NCHUNK * 1024 * 64;
  (void)wqkv_f; (void)wout_f; (void)wm1_f; (void)wm2_f; (void)temp_f; (void)bm1_f;

  ConvArgs ca;
  int acc = 0;
  for (int i = 0; i < 13; ++i) {
    ca.src[i] = d_in[i];
    ca.off[i] = acc;
    acc += (i < n_in) ? in_sizes[i] : 0;
  }
  ca.off[13] = acc;
  conv_prep_kernel<<<(acc + 255) / 256, 256, 0, stream>>>(
      ca, x_f, acc, wqkv_b, wout_b, wm1_b, wm2_b, qscale, part1p);

  qkv_fused_kernel<<<dim3(512, 2), 256, 0, stream>>>(
      x_f, part1p, g1_f, be1_f, wqkv_b, qscale, qn, kn, vs);

  attn14_kernel<<<dim3(1024), 512, 0, stream>>>(qn, kn, vs, pO, plb);

  wout_kernel<<<512, 256, 0, stream>>>(wout_b, pO, plb, bout_f, x_f, xres, part2p);

  mlp_fused_kernel<<<512, 256, 0, stream>>>(
      d_in[0], xres, part2p, g2_f, be2_f, wm1_b, bm1_f, wm2_b, bm2_f, d_out);
}

// Round 12
// 204.751 us; speedup vs baseline: 1.0579x; 1.0052x over previous
//
#include <hip/hip_runtime.h>
#include <hip/hip_bf16.h>
#include <math.h>

// Problem constants (B=2, C=256, H=W=64, heads=8, hd=32, groups=32, hid=64)
#define NB 2
#define NC 256
#define NHEAD 8
#define HD 32
#define NPIX 4096
#define GEPS 1e-5f
#define NCHUNK 2          // j-split factor for attention (linear softmax => exact)
#define JLEN (NPIX / NCHUNK)

typedef short bf16x8 __attribute__((ext_vector_type(8)));
typedef float f32x4 __attribute__((ext_vector_type(4)));

typedef __attribute__((address_space(3))) unsigned int lds_u32;
typedef __attribute__((address_space(1))) const unsigned int glb_u32;

union U16x8 { uint4 u4; uint2 u2[2]; unsigned u32[4]; unsigned short us[8]; bf16x8 v; };

__device__ inline unsigned short tobf(float f) {  // round-to-nearest-even
  union { float f; unsigned u; } c; c.f = f;
  return (unsigned short)((c.u + 0x7FFFu + ((c.u >> 16) & 1u)) >> 16);
}
__device__ inline unsigned packtrunc(float lo, float hi) {  // truncating bf16 pack, 1 instr
  return __builtin_amdgcn_perm(__float_as_uint(hi), __float_as_uint(lo), 0x07060302u);
}
__device__ inline float geluf(float v) {
  return 0.5f * v * (1.f + erff(v * 0.70710678118654752f));
}
// gfx950 cross-lane swaps (MFMA-fragment redistribution primitives):
// P32: swap a[i+32]<->b[i]; P16: swap a[i+16]<->b[i] per 32-half.
__device__ inline void plane32(unsigned &a, unsigned &b) {
  asm("v_permlane32_swap_b32 %0, %1" : "+v"(a), "+v"(b));
}
__device__ inline void plane16(unsigned &a, unsigned &b) {
  asm("v_permlane16_swap_b32 %0, %1" : "+v"(a), "+v"(b));
}

// Per-block dtype self-detection (bf16 vs fp32 x): wave-0 ballot + broadcast.
__device__ inline int detect_bf(const void* xraw) {
  __shared__ int flg;
  int t = threadIdx.x;
  if (t < 64) {
    unsigned short h = ((const unsigned short*)xraw)[2 * t];
    unsigned e = (h >> 7) & 0xFFu;
    int weird = (e < 113u || e > 140u) ? 1 : 0;
    unsigned long long m = __ballot(weird);
    if (t == 0) flg = (__popcll(m) > 16) ? 0 : 1;
  }
  __syncthreads();
  return flg;
}

struct ConvArgs { const void* src[13]; int off[14]; };

__device__ inline float ldsrc(const void* p, int idx, int bf) {
  if (bf) {
    unsigned v = ((const unsigned short*)p)[idx];
    return __uint_as_float(v << 16);
  }
  return ((const float*)p)[idx];
}

// ---------------------------------------------------------------------------
// Fused convert + prep + GN1 block-partials (shfl reduction, r7).
// ---------------------------------------------------------------------------
__global__ __launch_bounds__(256) void conv_prep_kernel(
    ConvArgs a, float* __restrict__ dstbase, int total,
    unsigned short* __restrict__ wqkv_b, unsigned short* __restrict__ wout_b,
    unsigned short* __restrict__ wm1_b, unsigned short* __restrict__ wm2_b,
    float* __restrict__ qscale, float* __restrict__ part1p) {
  int bf = detect_bf(a.src[0]);
  int blk = blockIdx.x, t = threadIdx.x;
  int i = blk * 256 + t;
  float val = 0.f;
  if (i < total) {
    int s = 0;
    while (i >= a.off[s + 1]) ++s;
    val = ldsrc(a.src[s], i - a.off[s], bf);
    dstbase[i] = val;
  }
  // GN1 partials (x = segment 0, exactly blocks 0..8191)
  if (blk < 8192) {
    float s = val, s2 = val * val;
#pragma unroll
    for (int o = 32; o > 0; o >>= 1) {
      s += __shfl_down(s, o, 64);
      s2 += __shfl_down(s2, o, 64);
    }
    __shared__ float r4[4][2];
    if ((t & 63) == 0) { r4[t >> 6][0] = s; r4[t >> 6][1] = s2; }
    __syncthreads();
    if (t == 0) {
      part1p[blk * 2] = r4[0][0] + r4[1][0] + r4[2][0] + r4[3][0];
      part1p[blk * 2 + 1] = r4[0][1] + r4[1][1] + r4[2][1] + r4[3][1];
    }
  }
  // prep (reads raw sources)
  if (i < 196608) wqkv_b[i] = tobf(ldsrc(a.src[1], i, bf));
  else if (i < 262144) wout_b[i - 196608] = tobf(ldsrc(a.src[2], i - 196608, bf));
  else if (i < 278528) wm1_b[i - 262144] = tobf(ldsrc(a.src[9], i - 262144, bf));
  else if (i < 294912) wm2_b[i - 278528] = tobf(ldsrc(a.src[11], i - 278528, bf));
  if (i < 768) {
    if (i < 256) {
      float tc = fminf(fmaxf(ldsrc(a.src[4], i >> 5, bf), 1e-4f), 10.f);
      qscale[i] = tc * 1.4426950408889634f;
    } else qscale[i] = 1.0f;
  }
}

// ---------------------------------------------------------------------------
// GN stat finish (r11): reduce per-block partials -> per-group (mean, rsqrt)
// ONCE, instead of every consumer block re-reducing them (qkv re-read 32 KB
// x1024 blocks, mlp 64 KB x512 = ~66 MB redundant + 2 barriers/block).
// 64 groups x 32768 elements each for both GN1 (N=128) and GN2 (N=256).
// ---------------------------------------------------------------------------
__global__ __launch_bounds__(64) void gn_stats_kernel(
    const float* __restrict__ part, float* __restrict__ st, int N) {
  int g = blockIdx.x, lane = threadIdx.x;
  float s = 0.f, s2 = 0.f;
  for (int j = lane; j < N; j += 64) {
    s += part[(g * N + j) * 2];
    s2 += part[(g * N + j) * 2 + 1];
  }
#pragma unroll
  for (int o = 32; o > 0; o >>= 1) {
    s += __shfl_down(s, o, 64);
    s2 += __shfl_down(s2, o, 64);
  }
  if (lane == 0) {
    float mean = s * (1.f / 32768.f);
    float var = s2 * (1.f / 32768.f) - mean * mean;
    st[g * 2] = mean;
    st[g * 2 + 1] = rsqrtf(var + GEPS);
  }
}

// ---------------------------------------------------------------------------
// QKV mega-kernel, r11: GN1 stats now read directly from gnst (each thread
// needs only groups 2cg, 2cg+1) -- the 32KB/block partial re-reduction and
// its two __syncthreads are deleted. GEMM + outputs unchanged.
// ---------------------------------------------------------------------------
__global__ __launch_bounds__(256) void qkv_fused_kernel(
    const float* __restrict__ x_f, const float* __restrict__ gnst,
    const float* __restrict__ g1, const float* __restrict__ be1,
    const unsigned short* __restrict__ W, const float* __restrict__ qscale,
    unsigned short* __restrict__ qn, unsigned short* __restrict__ kn,
    unsigned short* __restrict__ vs) {
  int t = threadIdx.x;
  int w = t >> 6, lane = t & 63, l16 = lane & 15, quad = lane >> 4;
  int p0 = blockIdx.x * 16;
  int b = p0 >> 12;
  __shared__ unsigned short Ys[16][264];
  {
    int p = t & 15, cg = t >> 4;
    int n = (p0 & 4095) + p;
    int gg0 = (b * 32 + cg * 2) * 2;
    float m0 = gnst[gg0], i0 = gnst[gg0 + 1];
    float m1 = gnst[gg0 + 2], i1 = gnst[gg0 + 3];
    const float* src = x_f + ((size_t)b * NC + cg * 16) * NPIX + n;
    U16x8 lo, hi;
#pragma unroll
    for (int cc = 0; cc < 16; ++cc) {
      int c = cg * 16 + cc;
      float mean = (cc < 8) ? m0 : m1;
      float si_ = (cc < 8) ? i0 : i1;
      float gg = g1[c] * si_;
      float vv = (src[(size_t)cc * NPIX] - mean) * gg + be1[c];
      if (cc < 8) lo.us[cc] = tobf(vv); else hi.us[cc - 8] = tobf(vv);
    }
    *(uint4*)&Ys[p][cg * 16] = lo.u4;
    *(uint4*)&Ys[p][cg * 16 + 8] = hi.u4;
  }
  __syncthreads();
  int ob = blockIdx.y * 384 + w * 96;
  f32x4 acc[6] = {};
#pragma unroll
  for (int k0 = 0; k0 < 256; k0 += 32) {
    U16x8 bfr; bfr.u4 = *(const uint4*)&Ys[l16][k0 + quad * 8];
#pragma unroll
    for (int ot = 0; ot < 6; ++ot) {
      U16x8 af;
      af.u4 = *(const uint4*)(W + (size_t)(ob + ot * 16 + l16) * 256 + k0 + quad * 8);
      acc[ot] = __builtin_amdgcn_mfma_f32_16x16x32_bf16(af.v, bfr.v, acc[ot], 0, 0, 0);
    }
  }
  int n = (p0 & 4095) + l16;
#pragma unroll
  for (int ot = 0; ot < 6; ++ot) {
    int oc = ob + ot * 16 + quad * 4;
    float v[4];
#pragma unroll
    for (int r = 0; r < 4; ++r) v[r] = acc[ot][r] * qscale[oc + r];
    int sec = oc >> 8;
    int c = oc & 255;
    if (sec < 2) {
      int hh = c >> 5, d = c & 31;
      unsigned short* base = sec == 0 ? qn : kn;
      uint2 pk;
      pk.x = (unsigned)tobf(v[0]) | ((unsigned)tobf(v[1]) << 16);
      pk.y = (unsigned)tobf(v[2]) | ((unsigned)tobf(v[3]) << 16);
      *(uint2*)(base + ((size_t)(b * NHEAD + hh) * NPIX + n) * HD + d) = pk;
    } else {
#pragma unroll
      for (int r = 0; r < 4; ++r)
        vs[((size_t)(b * NC + c + r)) * NPIX + n] = tobf(v[r]);
    }
  }
}

// ---------------------------------------------------------------------------
// MFMA flash attention v14 (round-6 best): in-register P via permlane
// (zero bank conflicts) + 2-tile unroll for intra-wave ILP. Unchanged.
// ---------------------------------------------------------------------------
__global__ __launch_bounds__(512) void attn14_kernel(
    const unsigned short* __restrict__ qn, const unsigned short* __restrict__ kn,
    const unsigned short* __restrict__ vs, float* __restrict__ pO,
    float* __restrict__ pl) {
  // Bijective XCD-pinned decode: HW round-robins consecutive block ids over
  // the 8 XCDs (f&7). Streams s = (chunk,h,b); 4 streams per XCD.
  int f = blockIdx.x;                   // 0..1023
  int xcd = f & 7, slot = f >> 3;       // slot 0..127
  int s = xcd + ((slot >> 5) << 3);     // stream 0..31
  int iblk = slot & 31;
  int chunk = s & 1;
  int h = (s >> 1) & 7;
  int b = s >> 4;
  int i0 = iblk * 128;
  int jbase = chunk * JLEN;
  int bh = b * NHEAD + h;
  int t = threadIdx.x;
  int w = t >> 6, lane = t & 63, l16 = lane & 15, quad = lane >> 4;

  __shared__ unsigned short Kt[2][4096];   // [dbuf][tileA|tileB], swizzled
  __shared__ unsigned short Vt[2][4096];

  U16x8 qf;
  qf.u4 = *(const uint4*)(qn + ((size_t)bh * NPIX + i0 + w * 16 + l16) * HD + quad * 8);
  U16x8 ones;
#pragma unroll
  for (int j = 0; j < 8; ++j) ones.us[j] = 0x3F80;

  const unsigned short* gp;
  lds_u32* dstA[2];                      // half A dst, static-indexed (rule #20)
  lds_u32* dstB[2];                      // half B dst
  if (w < 4) {
    int kj = (w << 4) + (lane >> 2);
    int kg = (lane & 3) ^ ((kj >> 1) & 3);
    gp = kn + ((size_t)bh * NPIX + jbase + kj) * HD + kg * 8;
    dstA[0] = (lds_u32*)&Kt[0][w * 512];
    dstA[1] = (lds_u32*)&Kt[1][w * 512];
    dstB[0] = (lds_u32*)&Kt[0][2048 + w * 512];
    dstB[1] = (lds_u32*)&Kt[1][2048 + w * 512];
  } else {
    int vd = ((w - 4) << 3) + (lane >> 3);
    int vg = (lane & 7) ^ (vd & 7);
    gp = vs + ((size_t)(b * NC + h * HD + vd)) * NPIX + jbase + vg * 8;
    dstA[0] = (lds_u32*)&Vt[0][(w - 4) * 512];
    dstA[1] = (lds_u32*)&Vt[1][(w - 4) * 512];
    dstB[0] = (lds_u32*)&Vt[0][2048 + (w - 4) * 512];
    dstB[1] = (lds_u32*)&Vt[1][2048 + (w - 4) * 512];
  }
  int ghalf = (w < 4) ? 64 * HD : 64;    // elements between tile t and t+1
  int gstep = 2 * ghalf;                 // advance per super-iteration

  f32x4 o0 = {0.f, 0.f, 0.f, 0.f}, o1 = {0.f, 0.f, 0.f, 0.f};
  f32x4 lacc = {0.f, 0.f, 0.f, 0.f};
  const f32x4 zf = {0.f, 0.f, 0.f, 0.f};

  int sp = (quad ^ ((l16 >> 1) & 3)) * 8;

  // Prologue: DMA tiles 0,1 -> buf 0 (halves A,B).
  __builtin_amdgcn_global_load_lds((glb_u32*)gp, dstA[0], 16, 0, 0);
  __builtin_amdgcn_global_load_lds((glb_u32*)(gp + ghalf), dstB[0], 16, 0, 0);
  gp += gstep;

  // exp+permlane+PV for one tile (base = LDS offset of tile half).
#define SOFTPV(ST, BASE)                                                        \
  {                                                                             \
    unsigned X0 = packtrunc(__builtin_amdgcn_exp2f(ST[0][0]),                   \
                            __builtin_amdgcn_exp2f(ST[0][1]));                  \
    unsigned Y0 = packtrunc(__builtin_amdgcn_exp2f(ST[0][2]),                   \
                            __builtin_amdgcn_exp2f(ST[0][3]));                  \
    unsigned X1 = packtrunc(__builtin_amdgcn_exp2f(ST[1][0]),                   \
                            __builtin_amdgcn_exp2f(ST[1][1]));                  \
    unsigned Y1 = packtrunc(__builtin_amdgcn_exp2f(ST[1][2]),                   \
                            __builtin_amdgcn_exp2f(ST[1][3]));                  \
    unsigned X2 = packtrunc(__builtin_amdgcn_exp2f(ST[2][0]),                   \
                            __builtin_amdgcn_exp2f(ST[2][1]));                  \
    unsigned Y2 = packtrunc(__builtin_amdgcn_exp2f(ST[2][2]),                   \
                            __builtin_amdgcn_exp2f(ST[2][3]));                  \
    unsigned X3 = packtrunc(__builtin_amdgcn_exp2f(ST[3][0]),                   \
                            __builtin_amdgcn_exp2f(ST[3][1]));                  \
    unsigned Y3 = packtrunc(__builtin_amdgcn_exp2f(ST[3][2]),                   \
                            __builtin_amdgcn_exp2f(ST[3][3]));                  \
    plane32(X0, X1); plane16(X0, X1);                                           \
    plane32(Y0, Y1); plane16(Y0, Y1);                                           \
    plane32(X2, X3); plane16(X2, X3);                                           \
    plane32(Y2, Y3); plane16(Y2, Y3);                                           \
    __builtin_amdgcn_s_setprio(1);                                              \
    {                                                                           \
      U16x8 pb; pb.u32[0] = X0; pb.u32[1] = Y0; pb.u32[2] = X1; pb.u32[3] = Y1; \
      int vp = (quad ^ (l16 & 7)) * 8;                                          \
      U16x8 va; va.u4 = *(const uint4*)&(BASE)[l16 * 64 + vp];                  \
      U16x8 vb2; vb2.u4 = *(const uint4*)&(BASE)[(16 + l16) * 64 + vp];         \
      o0 = __builtin_amdgcn_mfma_f32_16x16x32_bf16(va.v, pb.v, o0, 0, 0, 0);    \
      o1 = __builtin_amdgcn_mfma_f32_16x16x32_bf16(vb2.v, pb.v, o1, 0, 0, 0);   \
      lacc = __builtin_amdgcn_mfma_f32_16x16x32_bf16(ones.v, pb.v, lacc, 0, 0, 0);\
    }                                                                           \
    {                                                                           \
      U16x8 pb; pb.u32[0] = X2; pb.u32[1] = Y2; pb.u32[2] = X3; pb.u32[3] = Y3; \
      int vp = ((4 + quad) ^ (l16 & 7)) * 8;                                    \
      U16x8 va; va.u4 = *(const uint4*)&(BASE)[l16 * 64 + vp];                  \
      U16x8 vb2; vb2.u4 = *(const uint4*)&(BASE)[(16 + l16) * 64 + vp];         \
      o0 = __builtin_amdgcn_mfma_f32_16x16x32_bf16(va.v, pb.v, o0, 0, 0, 0);    \
      o1 = __builtin_amdgcn_mfma_f32_16x16x32_bf16(vb2.v, pb.v, o1, 0, 0, 0);   \
      lacc = __builtin_amdgcn_mfma_f32_16x16x32_bf16(ones.v, pb.v, lacc, 0, 0, 0);\
    }                                                                           \
    __builtin_amdgcn_s_setprio(0);                                              \
  }

  // One super-iteration: tiles {2s,2s+1} from buf CUR; stage {2s+2,2s+3}.
#define ATTN_STEP(CUR, ISSUE)                                                   \
  {                                                                             \
    asm volatile("s_waitcnt vmcnt(0)" ::: "memory");                            \
    __builtin_amdgcn_s_barrier();                                               \
    if (ISSUE) {                                                                \
      __builtin_amdgcn_global_load_lds((glb_u32*)gp, dstA[(CUR) ^ 1], 16, 0, 0);\
      __builtin_amdgcn_global_load_lds((glb_u32*)(gp + ghalf), dstB[(CUR) ^ 1], \
                                       16, 0, 0);                               \
      gp += gstep;                                                              \
    }                                                                           \
    __builtin_amdgcn_sched_barrier(0);                                          \
    f32x4 stA[4], stB[4];                                                       \
    __builtin_amdgcn_s_setprio(1);                                              \
    _Pragma("unroll")                                                           \
    for (int jj = 0; jj < 4; ++jj) {                                            \
      U16x8 kf; kf.u4 = *(const uint4*)&Kt[CUR][(jj * 16 + l16) * 32 + sp];     \
      stA[jj] = __builtin_amdgcn_mfma_f32_16x16x32_bf16(kf.v, qf.v, zf, 0, 0, 0);\
    }                                                                           \
    _Pragma("unroll")                                                           \
    for (int jj = 0; jj < 4; ++jj) {                                            \
      U16x8 kf;                                                                 \
      kf.u4 = *(const uint4*)&Kt[CUR][2048 + (jj * 16 + l16) * 32 + sp];        \
      stB[jj] = __builtin_amdgcn_mfma_f32_16x16x32_bf16(kf.v, qf.v, zf, 0, 0, 0);\
    }                                                                           \
    __builtin_amdgcn_s_setprio(0);                                              \
    SOFTPV(stA, (&Vt[CUR][0]))                                                  \
    SOFTPV(stB, (&Vt[CUR][2048]))                                               \
  }

  // 32 tiles = 16 super-iterations: 14 rolled + 2 peeled (last stages none).
#pragma unroll 1
  for (int it = 0; it < 7; ++it) {
    ATTN_STEP(0, 1)
    ATTN_STEP(1, 1)
  }
  ATTN_STEP(0, 1)
  ATTN_STEP(1, 0)
#undef ATTN_STEP
#undef SOFTPV

  int pr = bh * 64 + iblk * 2 + (w >> 2);
  float* ob = pO + ((size_t)chunk * 1024 + pr) * 2048;
  int icol = (w & 3) * 16 + l16;
#pragma unroll
  for (int r = 0; r < 4; ++r) {
    ob[(quad * 4 + r) * 64 + icol] = o0[r];
    ob[(16 + quad * 4 + r) * 64 + icol] = o1[r];
  }
  if (quad == 0)
    pl[((size_t)chunk * 1024 + pr) * 64 + icol] = lacc[0];
}

// ---------------------------------------------------------------------------
// wout GEMM with INLINE combine (round-9 proven config, unchanged).
// ---------------------------------------------------------------------------
__global__ __launch_bounds__(256) void wout_kernel(
    const unsigned short* __restrict__ W, const float* __restrict__ pO,
    const float* __restrict__ pl, const float* __restrict__ bias,
    const float* __restrict__ res, float* __restrict__ xres_t,
    float* __restrict__ part2p) {
  int t = threadIdx.x;
  int w = t >> 6, lane = t & 63, l16 = lane & 15, quad = lane >> 4;
  int p = blockIdx.x * 16 + l16;
  int b = p >> 12, n = p & 4095;
  int i = p & 63, iblk = (p >> 6) & 63;
  int ob = w * 64;
  float rinv8[8];
#pragma unroll
  for (int hh = 0; hh < 8; ++hh) {
    size_t pr = (size_t)(b * NHEAD + hh) * 64 + iblk;
    float l = pl[pr * 64 + i] + pl[(1024 + pr) * 64 + i];
    rinv8[hh] = 1.f / l;
  }
  f32x4 acc[4] = {};
#pragma unroll
  for (int k0 = 0; k0 < 256; k0 += 32) {
    int hh = k0 >> 5;
    const float* q0 = pO + ((size_t)(b * NHEAD + hh) * 64 + iblk) * 2048 + quad * 8 * 64 + i;
    const float* q1 = q0 + (size_t)1024 * 2048;
    float rv = rinv8[hh];
    U16x8 bfr;
#pragma unroll
    for (int u = 0; u < 4; ++u) {
      float va = (q0[(2 * u) * 64] + q1[(2 * u) * 64]) * rv;
      float vb = (q0[(2 * u + 1) * 64] + q1[(2 * u + 1) * 64]) * rv;
      bfr.u32[u] = packtrunc(va, vb);
    }
#pragma unroll
    for (int ot = 0; ot < 4; ++ot) {
      U16x8 af;
      af.u4 = *(const uint4*)(W + (size_t)(ob + ot * 16 + l16) * 256 + k0 + quad * 8);
      acc[ot] = __builtin_amdgcn_mfma_f32_16x16x32_bf16(af.v, bfr.v, acc[ot], 0, 0, 0);
    }
  }
  __shared__ float sb[256][4][2];
#pragma unroll
  for (int ot = 0; ot < 4; ++ot) {
    int oc = ob + ot * 16 + quad * 4;
    float s = 0.f, s2 = 0.f;
    float v4[4];
#pragma unroll
    for (int r = 0; r < 4; ++r) {
      float vv = acc[ot][r] + bias[oc + r] + res[((size_t)(b * NC + oc + r)) * NPIX + n];
      v4[r] = vv;
      s += vv; s2 += vv * vv;
    }
    *(float4*)&xres_t[(size_t)p * NC + oc] = make_float4(v4[0], v4[1], v4[2], v4[3]);
    sb[t][ot][0] = s; sb[t][ot][1] = s2;
  }
  __syncthreads();
  if (t < 32) {  // group g == t; channels [g*8, g*8+8)
    int ww = t >> 3, rem = t & 7, ot = rem >> 1, qp = rem & 1;
    float s = 0.f, s2 = 0.f;
#pragma unroll
    for (int q = 2 * qp; q < 2 * qp + 2; ++q)
      for (int l = 0; l < 16; ++l) {
        int tt = ww * 64 + q * 16 + l;
        s += sb[tt][ot][0]; s2 += sb[tt][ot][1];
      }
    size_t idx = ((size_t)(b * 32 + t) * 256 + (blockIdx.x & 255)) * 2;
    part2p[idx] = s; part2p[idx + 1] = s2;
  }
}

// ---------------------------------------------------------------------------
// MLP mega-kernel, r11: GN2 stats read directly from gnst2 (groups 2cg,
// 2cg+1 per thread) -- 64KB/block partial re-reduction + 2 barriers deleted.
// ---------------------------------------------------------------------------
__global__ __launch_bounds__(256) void mlp_fused_kernel(
    const void* __restrict__ xraw, const float* __restrict__ xres_t,
    const float* __restrict__ gnst, const float* __restrict__ g2,
    const float* __restrict__ be2, const unsigned short* __restrict__ W1,
    const float* __restrict__ b1, const unsigned short* __restrict__ W2,
    const float* __restrict__ b2, void* __restrict__ dout) {
  int wbf = detect_bf(xraw);
  int t = threadIdx.x;
  int w = t >> 6, lane = t & 63, l16 = lane & 15, quad = lane >> 4;
  int p0 = blockIdx.x * 16;
  int b = p0 >> 12;
  __shared__ float Xs[16][261];
  __shared__ unsigned short Ys[16][264];
  {
    int p = t >> 4, cg = t & 15;  // coalesced: 16 consecutive t span one row
    int gg0 = (b * 32 + cg * 2) * 2;
    float m0 = gnst[gg0], i0 = gnst[gg0 + 1];
    float m1 = gnst[gg0 + 2], i1 = gnst[gg0 + 3];
    const float* src = xres_t + (size_t)(p0 + p) * NC + cg * 16;
    U16x8 lo, hi;
#pragma unroll
    for (int cc = 0; cc < 16; ++cc) {
      int c = cg * 16 + cc;
      float v = src[cc];
      Xs[p][c] = v;
      float mean = (cc < 8) ? m0 : m1;
      float si_ = (cc < 8) ? i0 : i1;
      float yv = (v - mean) * (g2[c] * si_) + be2[c];
      if (cc < 8) lo.us[cc] = tobf(yv); else hi.us[cc - 8] = tobf(yv);
    }
    *(uint4*)&Ys[p][cg * 16] = lo.u4;
    *(uint4*)&Ys[p][cg * 16 + 8] = hi.u4;
  }
  __syncthreads();
  f32x4 a1 = {0.f, 0.f, 0.f, 0.f};
#pragma unroll
  for (int k0 = 0; k0 < 256; k0 += 32) {
    U16x8 bfr; bfr.u4 = *(const uint4*)&Ys[l16][k0 + quad * 8];
    U16x8 af;
    af.u4 = *(const uint4*)(W1 + (size_t)(w * 16 + l16) * 256 + k0 + quad * 8);
    a1 = __builtin_amdgcn_mfma_f32_16x16x32_bf16(af.v, bfr.v, a1, 0, 0, 0);
  }
  __shared__ unsigned short Hs[16][72];
  {
    int oc = w * 16 + quad * 4;
    float h0 = geluf(a1[0] + b1[oc]),     h1 = geluf(a1[1] + b1[oc + 1]);
    float h2 = geluf(a1[2] + b1[oc + 2]), h3 = geluf(a1[3] + b1[oc + 3]);
    uint2 pk;
    pk.x = (unsigned)tobf(h0) | ((unsigned)tobf(h1) << 16);
    pk.y = (unsigned)tobf(h2) | ((unsigned)tobf(h3) << 16);
    *(uint2*)&Hs[l16][oc] = pk;
  }
  __syncthreads();
  f32x4 a2[4] = {};
#pragma unroll
  for (int k0 = 0; k0 < 64; k0 += 32) {
    U16x8 bfr; bfr.u4 = *(const uint4*)&Hs[l16][k0 + quad * 8];
#pragma unroll
    for (int ot = 0; ot < 4; ++ot) {
      U16x8 af;
      af.u4 = *(const uint4*)(W2 + (size_t)(w * 64 + ot * 16 + l16) * 64 + k0 + quad * 8);
      a2[ot] = __builtin_amdgcn_mfma_f32_16x16x32_bf16(af.v, bfr.v, a2[ot], 0, 0, 0);
    }
  }
  int n = (p0 & 4095) + l16;
#pragma unroll
  for (int ot = 0; ot < 4; ++ot) {
    int oc = w * 64 + ot * 16 + quad * 4;
#pragma unroll
    for (int r = 0; r < 4; ++r) {
      float v = a2[ot][r] + b2[oc + r] + Xs[l16][oc + r];
      size_t oidx = ((size_t)(b * NC + oc + r)) * NPIX + n;
      if (wbf) ((__hip_bfloat16*)dout)[oidx] = __float2bfloat16(v);
      else ((float*)dout)[oidx] = v;
    }
  }
}

// ---------------------------------------------------------------------------
// Launch pipeline: 7 kernels (2 tiny gn_stats hoists).
// ---------------------------------------------------------------------------
extern "C" void kernel_launch(void* const* d_in, const int* in_sizes, int n_in,
                              void* d_out, int out_size, void* d_ws, size_t ws_size,
                              hipStream_t stream) {
  float* ws = (float*)d_ws;
  size_t off = 16;
  float* x_f    = ws + off; off += (size_t)NB * NC * NPIX;
  float* wqkv_f = ws + off; off += 768 * 256;
  float* wout_f = ws + off; off += 256 * 256;
  float* bout_f = ws + off; off += 256;
  float* temp_f = ws + off; off += 8;
  float* g1_f   = ws + off; off += 256;
  float* be1_f  = ws + off; off += 256;
  float* g2_f   = ws + off; off += 256;
  float* be2_f  = ws + off; off += 256;
  float* wm1_f  = ws + off; off += 64 * 256;
  float* bm1_f  = ws + off; off += 64;
  float* wm2_f  = ws + off; off += 256 * 64;
  float* bm2_f  = ws + off; off += 256;
  float* xres   = ws + off; off += (size_t)NB * NC * NPIX;  // pixel-major [8192][256]
  unsigned short* qn     = (unsigned short*)(ws + off); off += 1048576;  // [16][4096][32]
  unsigned short* kn     = (unsigned short*)(ws + off); off += 1048576;  // [16][4096][32]
  unsigned short* vs     = (unsigned short*)(ws + off); off += 1048576;  // [2][256][4096]
  unsigned short* wqkv_b = (unsigned short*)(ws + off); off += 98304;
  unsigned short* wout_b = (unsigned short*)(ws + off); off += 32768;
  unsigned short* wm1_b  = (unsigned short*)(ws + off); off += 8192;
  unsigned short* wm2_b  = (unsigned short*)(ws + off); off += 8192;
  float* qscale = ws + off; off += 768;
  float* part1p = ws + off; off += 16384;   // [8192][2] GN1 block partials
  float* part2p = ws + off; off += 65536;   // [64 bg][256 blk][2] GN2 partials
  float* gnst1  = ws + off; off += 128;     // [64 groups][mean, rsqrt]
  float* gnst2  = ws + off; off += 128;
  float* pO     = ws + off; off += (size_t)NCHUNK * 1024 * 2048;
  float* plb    = ws + off; off += (size_t)NCHUNK * 1024 * 64;
  (void)wqkv_f; (void)wout_f; (void)wm1_f; (void)wm2_f; (void)temp_f; (void)bm1_f;

  ConvArgs ca;
  int acc = 0;
  for (int i = 0; i < 13; ++i) {
    ca.src[i] = d_in[i];
    ca.off[i] = acc;
    acc += (i < n_in) ? in_sizes[i] : 0;
  }
  ca.off[13] = acc;
  conv_prep_kernel<<<(acc + 255) / 256, 256, 0, stream>>>(
      ca, x_f, acc, wqkv_b, wout_b, wm1_b, wm2_b, qscale, part1p);

  gn_stats_kernel<<<64, 64, 0, stream>>>(part1p, gnst1, 128);

  qkv_fused_kernel<<<dim3(512, 2), 256, 0, stream>>>(
      x_f, gnst1, g1_f, be1_f, wqkv_b, qscale, qn, kn, vs);

  attn14_kernel<<<dim3(1024), 512, 0, stream>>>(qn, kn, vs, pO, plb);

  wout_kernel<<<512, 256, 0, stream>>>(wout_b, pO, plb, bout_f, x_f, xres, part2p);

  gn_stats_kernel<<<64, 64, 0, stream>>>(part2p, gnst2, 256);

  mlp_fused_kernel<<<512, 256, 0, stream>>>(
      d_in[0], xres, gnst2, g2_f, be2_f, wm1_b, bm1_f, wm2_b, bm2_f, d_out);
}

// Round 14
// 198.567 us; speedup vs baseline: 1.0909x; 1.0311x over previous
//
#include <hip/hip_runtime.h>
#include <hip/hip_bf16.h>
#include <math.h>

// Problem constants (B=2, C=256, H=W=64, heads=8, hd=32, groups=32, hid=64)
#define NB 2
#define NC 256
#define NHEAD 8
#define HD 32
#define NPIX 4096
#define GEPS 1e-5f
#define NCHUNK 2          // j-split factor for attention (linear softmax => exact)
#define JLEN (NPIX / NCHUNK)

typedef short bf16x8 __attribute__((ext_vector_type(8)));
typedef float f32x4 __attribute__((ext_vector_type(4)));

typedef __attribute__((address_space(3))) unsigned int lds_u32;
typedef __attribute__((address_space(1))) const unsigned int glb_u32;

union U16x8 { uint4 u4; uint2 u2[2]; unsigned u32[4]; unsigned short us[8]; bf16x8 v; };

__device__ inline unsigned short tobf(float f) {  // round-to-nearest-even
  union { float f; unsigned u; } c; c.f = f;
  return (unsigned short)((c.u + 0x7FFFu + ((c.u >> 16) & 1u)) >> 16);
}
__device__ inline unsigned packtrunc(float lo, float hi) {  // truncating bf16 pack, 1 instr
  return __builtin_amdgcn_perm(__float_as_uint(hi), __float_as_uint(lo), 0x07060302u);
}
__device__ inline float bf2f(unsigned short h) {
  return __uint_as_float((unsigned)h << 16);
}
__device__ inline float geluf(float v) {
  return 0.5f * v * (1.f + erff(v * 0.70710678118654752f));
}
// gfx950 cross-lane swaps (MFMA-fragment redistribution primitives):
// P32: swap a[i+32]<->b[i]; P16: swap a[i+16]<->b[i] per 32-half.
__device__ inline void plane32(unsigned &a, unsigned &b) {
  asm("v_permlane32_swap_b32 %0, %1" : "+v"(a), "+v"(b));
}
__device__ inline void plane16(unsigned &a, unsigned &b) {
  asm("v_permlane16_swap_b32 %0, %1" : "+v"(a), "+v"(b));
}

// Per-block dtype self-detection (bf16 vs fp32 x): wave-0 ballot + broadcast.
__device__ inline int detect_bf(const void* xraw) {
  __shared__ int flg;
  int t = threadIdx.x;
  if (t < 64) {
    unsigned short h = ((const unsigned short*)xraw)[2 * t];
    unsigned e = (h >> 7) & 0xFFu;
    int weird = (e < 113u || e > 140u) ? 1 : 0;
    unsigned long long m = __ballot(weird);
    if (t == 0) flg = (__popcll(m) > 16) ? 0 : 1;
  }
  __syncthreads();
  return flg;
}

struct ConvArgs { const void* src[13]; int off[14]; };

__device__ inline float ldsrc(const void* p, int idx, int bf) {
  if (bf) {
    unsigned v = ((const unsigned short*)p)[idx];
    return __uint_as_float(v << 16);
  }
  return ((const float*)p)[idx];
}

// ---------------------------------------------------------------------------
// Fused convert + prep + GN1 block-partials (shfl reduction, r7).
// ---------------------------------------------------------------------------
__global__ __launch_bounds__(256) void conv_prep_kernel(
    ConvArgs a, float* __restrict__ dstbase, int total,
    unsigned short* __restrict__ wqkv_b, unsigned short* __restrict__ wout_b,
    unsigned short* __restrict__ wm1_b, unsigned short* __restrict__ wm2_b,
    float* __restrict__ qscale, float* __restrict__ part1p) {
  int bf = detect_bf(a.src[0]);
  int blk = blockIdx.x, t = threadIdx.x;
  int i = blk * 256 + t;
  float val = 0.f;
  if (i < total) {
    int s = 0;
    while (i >= a.off[s + 1]) ++s;
    val = ldsrc(a.src[s], i - a.off[s], bf);
    dstbase[i] = val;
  }
  // GN1 partials (x = segment 0, exactly blocks 0..8191)
  if (blk < 8192) {
    float s = val, s2 = val * val;
#pragma unroll
    for (int o = 32; o > 0; o >>= 1) {
      s += __shfl_down(s, o, 64);
      s2 += __shfl_down(s2, o, 64);
    }
    __shared__ float r4[4][2];
    if ((t & 63) == 0) { r4[t >> 6][0] = s; r4[t >> 6][1] = s2; }
    __syncthreads();
    if (t == 0) {
      part1p[blk * 2] = r4[0][0] + r4[1][0] + r4[2][0] + r4[3][0];
      part1p[blk * 2 + 1] = r4[0][1] + r4[1][1] + r4[2][1] + r4[3][1];
    }
  }
  // prep (reads raw sources)
  if (i < 196608) wqkv_b[i] = tobf(ldsrc(a.src[1], i, bf));
  else if (i < 262144) wout_b[i - 196608] = tobf(ldsrc(a.src[2], i - 196608, bf));
  else if (i < 278528) wm1_b[i - 262144] = tobf(ldsrc(a.src[9], i - 262144, bf));
  else if (i < 294912) wm2_b[i - 278528] = tobf(ldsrc(a.src[11], i - 278528, bf));
  if (i < 768) {
    if (i < 256) {
      float tc = fminf(fmaxf(ldsrc(a.src[4], i >> 5, bf), 1e-4f), 10.f);
      qscale[i] = tc * 1.4426950408889634f;
    } else qscale[i] = 1.0f;
  }
}

// ---------------------------------------------------------------------------
// GN stat finish (r11): per-group (mean, rsqrt) computed once.
// ---------------------------------------------------------------------------
__global__ __launch_bounds__(64) void gn_stats_kernel(
    const float* __restrict__ part, float* __restrict__ st, int N) {
  int g = blockIdx.x, lane = threadIdx.x;
  float s = 0.f, s2 = 0.f;
  for (int j = lane; j < N; j += 64) {
    s += part[(g * N + j) * 2];
    s2 += part[(g * N + j) * 2 + 1];
  }
#pragma unroll
  for (int o = 32; o > 0; o >>= 1) {
    s += __shfl_down(s, o, 64);
    s2 += __shfl_down(s2, o, 64);
  }
  if (lane == 0) {
    float mean = s * (1.f / 32768.f);
    float var = s2 * (1.f / 32768.f) - mean * mean;
    st[g * 2] = mean;
    st[g * 2 + 1] = rsqrtf(var + GEPS);
  }
}

// ---------------------------------------------------------------------------
// QKV mega-kernel (r11 config, unchanged).
// ---------------------------------------------------------------------------
__global__ __launch_bounds__(256) void qkv_fused_kernel(
    const float* __restrict__ x_f, const float* __restrict__ gnst,
    const float* __restrict__ g1, const float* __restrict__ be1,
    const unsigned short* __restrict__ W, const float* __restrict__ qscale,
    unsigned short* __restrict__ qn, unsigned short* __restrict__ kn,
    unsigned short* __restrict__ vs) {
  int t = threadIdx.x;
  int w = t >> 6, lane = t & 63, l16 = lane & 15, quad = lane >> 4;
  int p0 = blockIdx.x * 16;
  int b = p0 >> 12;
  __shared__ unsigned short Ys[16][264];
  {
    int p = t & 15, cg = t >> 4;
    int n = (p0 & 4095) + p;
    int gg0 = (b * 32 + cg * 2) * 2;
    float m0 = gnst[gg0], i0 = gnst[gg0 + 1];
    float m1 = gnst[gg0 + 2], i1 = gnst[gg0 + 3];
    const float* src = x_f + ((size_t)b * NC + cg * 16) * NPIX + n;
    U16x8 lo, hi;
#pragma unroll
    for (int cc = 0; cc < 16; ++cc) {
      int c = cg * 16 + cc;
      float mean = (cc < 8) ? m0 : m1;
      float si_ = (cc < 8) ? i0 : i1;
      float gg = g1[c] * si_;
      float vv = (src[(size_t)cc * NPIX] - mean) * gg + be1[c];
      if (cc < 8) lo.us[cc] = tobf(vv); else hi.us[cc - 8] = tobf(vv);
    }
    *(uint4*)&Ys[p][cg * 16] = lo.u4;
    *(uint4*)&Ys[p][cg * 16 + 8] = hi.u4;
  }
  __syncthreads();
  int ob = blockIdx.y * 384 + w * 96;
  f32x4 acc[6] = {};
#pragma unroll
  for (int k0 = 0; k0 < 256; k0 += 32) {
    U16x8 bfr; bfr.u4 = *(const uint4*)&Ys[l16][k0 + quad * 8];
#pragma unroll
    for (int ot = 0; ot < 6; ++ot) {
      U16x8 af;
      af.u4 = *(const uint4*)(W + (size_t)(ob + ot * 16 + l16) * 256 + k0 + quad * 8);
      acc[ot] = __builtin_amdgcn_mfma_f32_16x16x32_bf16(af.v, bfr.v, acc[ot], 0, 0, 0);
    }
  }
  int n = (p0 & 4095) + l16;
#pragma unroll
  for (int ot = 0; ot < 6; ++ot) {
    int oc = ob + ot * 16 + quad * 4;
    float v[4];
#pragma unroll
    for (int r = 0; r < 4; ++r) v[r] = acc[ot][r] * qscale[oc + r];
    int sec = oc >> 8;
    int c = oc & 255;
    if (sec < 2) {
      int hh = c >> 5, d = c & 31;
      unsigned short* base = sec == 0 ? qn : kn;
      uint2 pk;
      pk.x = (unsigned)tobf(v[0]) | ((unsigned)tobf(v[1]) << 16);
      pk.y = (unsigned)tobf(v[2]) | ((unsigned)tobf(v[3]) << 16);
      *(uint2*)(base + ((size_t)(b * NHEAD + hh) * NPIX + n) * HD + d) = pk;
    } else {
#pragma unroll
      for (int r = 0; r < 4; ++r)
        vs[((size_t)(b * NC + c + r)) * NPIX + n] = tobf(v[r]);
    }
  }
}

// ---------------------------------------------------------------------------
// MFMA flash attention v15b: hot loop IDENTICAL to v14 (proven). Epilogue now
// writes pO as BF16 PIXEL-MAJOR [b][pix][chunk][h][d]: d = quad*4+r is
// contiguous -> two uint2 stores per thread. Halves pO traffic and gives
// wout contiguous 16B/lane fragment reads (4x fewer loads).
// ---------------------------------------------------------------------------
__global__ __launch_bounds__(512) void attn15b_kernel(
    const unsigned short* __restrict__ qn, const unsigned short* __restrict__ kn,
    const unsigned short* __restrict__ vs, unsigned short* __restrict__ pOb,
    float* __restrict__ pl) {
  // Bijective XCD-pinned decode: HW round-robins consecutive block ids over
  // the 8 XCDs (f&7). Streams s = (chunk,h,b); 4 streams per XCD.
  int f = blockIdx.x;                   // 0..1023
  int xcd = f & 7, slot = f >> 3;       // slot 0..127
  int s = xcd + ((slot >> 5) << 3);     // stream 0..31
  int iblk = slot & 31;
  int chunk = s & 1;
  int h = (s >> 1) & 7;
  int b = s >> 4;
  int i0 = iblk * 128;
  int jbase = chunk * JLEN;
  int bh = b * NHEAD + h;
  int t = threadIdx.x;
  int w = t >> 6, lane = t & 63, l16 = lane & 15, quad = lane >> 4;

  __shared__ unsigned short Kt[2][4096];   // [dbuf][tileA|tileB], swizzled
  __shared__ unsigned short Vt[2][4096];

  U16x8 qf;
  qf.u4 = *(const uint4*)(qn + ((size_t)bh * NPIX + i0 + w * 16 + l16) * HD + quad * 8);
  U16x8 ones;
#pragma unroll
  for (int j = 0; j < 8; ++j) ones.us[j] = 0x3F80;

  const unsigned short* gp;
  lds_u32* dstA[2];                      // half A dst, static-indexed (rule #20)
  lds_u32* dstB[2];                      // half B dst
  if (w < 4) {
    int kj = (w << 4) + (lane >> 2);
    int kg = (lane & 3) ^ ((kj >> 1) & 3);
    gp = kn + ((size_t)bh * NPIX + jbase + kj) * HD + kg * 8;
    dstA[0] = (lds_u32*)&Kt[0][w * 512];
    dstA[1] = (lds_u32*)&Kt[1][w * 512];
    dstB[0] = (lds_u32*)&Kt[0][2048 + w * 512];
    dstB[1] = (lds_u32*)&Kt[1][2048 + w * 512];
  } else {
    int vd = ((w - 4) << 3) + (lane >> 3);
    int vg = (lane & 7) ^ (vd & 7);
    gp = vs + ((size_t)(b * NC + h * HD + vd)) * NPIX + jbase + vg * 8;
    dstA[0] = (lds_u32*)&Vt[0][(w - 4) * 512];
    dstA[1] = (lds_u32*)&Vt[1][(w - 4) * 512];
    dstB[0] = (lds_u32*)&Vt[0][2048 + (w - 4) * 512];
    dstB[1] = (lds_u32*)&Vt[1][2048 + (w - 4) * 512];
  }
  int ghalf = (w < 4) ? 64 * HD : 64;    // elements between tile t and t+1
  int gstep = 2 * ghalf;                 // advance per super-iteration

  f32x4 o0 = {0.f, 0.f, 0.f, 0.f}, o1 = {0.f, 0.f, 0.f, 0.f};
  f32x4 lacc = {0.f, 0.f, 0.f, 0.f};
  const f32x4 zf = {0.f, 0.f, 0.f, 0.f};

  int sp = (quad ^ ((l16 >> 1) & 3)) * 8;

  // Prologue: DMA tiles 0,1 -> buf 0 (halves A,B).
  __builtin_amdgcn_global_load_lds((glb_u32*)gp, dstA[0], 16, 0, 0);
  __builtin_amdgcn_global_load_lds((glb_u32*)(gp + ghalf), dstB[0], 16, 0, 0);
  gp += gstep;

  // exp+permlane+PV for one tile (base = LDS offset of tile half).
#define SOFTPV(ST, BASE)                                                        \
  {                                                                             \
    unsigned X0 = packtrunc(__builtin_amdgcn_exp2f(ST[0][0]),                   \
                            __builtin_amdgcn_exp2f(ST[0][1]));                  \
    unsigned Y0 = packtrunc(__builtin_amdgcn_exp2f(ST[0][2]),                   \
                            __builtin_amdgcn_exp2f(ST[0][3]));                  \
    unsigned X1 = packtrunc(__builtin_amdgcn_exp2f(ST[1][0]),                   \
                            __builtin_amdgcn_exp2f(ST[1][1]));                  \
    unsigned Y1 = packtrunc(__builtin_amdgcn_exp2f(ST[1][2]),                   \
                            __builtin_amdgcn_exp2f(ST[1][3]));                  \
    unsigned X2 = packtrunc(__builtin_amdgcn_exp2f(ST[2][0]),                   \
                            __builtin_amdgcn_exp2f(ST[2][1]));                  \
    unsigned Y2 = packtrunc(__builtin_amdgcn_exp2f(ST[2][2]),                   \
                            __builtin_amdgcn_exp2f(ST[2][3]));                  \
    unsigned X3 = packtrunc(__builtin_amdgcn_exp2f(ST[3][0]),                   \
                            __builtin_amdgcn_exp2f(ST[3][1]));                  \
    unsigned Y3 = packtrunc(__builtin_amdgcn_exp2f(ST[3][2]),                   \
                            __builtin_amdgcn_exp2f(ST[3][3]));                  \
    plane32(X0, X1); plane16(X0, X1);                                           \
    plane32(Y0, Y1); plane16(Y0, Y1);                                           \
    plane32(X2, X3); plane16(X2, X3);                                           \
    plane32(Y2, Y3); plane16(Y2, Y3);                                           \
    __builtin_amdgcn_s_setprio(1);                                              \
    {                                                                           \
      U16x8 pb; pb.u32[0] = X0; pb.u32[1] = Y0; pb.u32[2] = X1; pb.u32[3] = Y1; \
      int vp = (quad ^ (l16 & 7)) * 8;                                          \
      U16x8 va; va.u4 = *(const uint4*)&(BASE)[l16 * 64 + vp];                  \
      U16x8 vb2; vb2.u4 = *(const uint4*)&(BASE)[(16 + l16) * 64 + vp];         \
      o0 = __builtin_amdgcn_mfma_f32_16x16x32_bf16(va.v, pb.v, o0, 0, 0, 0);    \
      o1 = __builtin_amdgcn_mfma_f32_16x16x32_bf16(vb2.v, pb.v, o1, 0, 0, 0);   \
      lacc = __builtin_amdgcn_mfma_f32_16x16x32_bf16(ones.v, pb.v, lacc, 0, 0, 0);\
    }                                                                           \
    {                                                                           \
      U16x8 pb; pb.u32[0] = X2; pb.u32[1] = Y2; pb.u32[2] = X3; pb.u32[3] = Y3; \
      int vp = ((4 + quad) ^ (l16 & 7)) * 8;                                    \
      U16x8 va; va.u4 = *(const uint4*)&(BASE)[l16 * 64 + vp];                  \
      U16x8 vb2; vb2.u4 = *(const uint4*)&(BASE)[(16 + l16) * 64 + vp];         \
      o0 = __builtin_amdgcn_mfma_f32_16x16x32_bf16(va.v, pb.v, o0, 0, 0, 0);    \
      o1 = __builtin_amdgcn_mfma_f32_16x16x32_bf16(vb2.v, pb.v, o1, 0, 0, 0);   \
      lacc = __builtin_amdgcn_mfma_f32_16x16x32_bf16(ones.v, pb.v, lacc, 0, 0, 0);\
    }                                                                           \
    __builtin_amdgcn_s_setprio(0);                                              \
  }

  // One super-iteration: tiles {2s,2s+1} from buf CUR; stage {2s+2,2s+3}.
#define ATTN_STEP(CUR, ISSUE)                                                   \
  {                                                                             \
    asm volatile("s_waitcnt vmcnt(0)" ::: "memory");                            \
    __builtin_amdgcn_s_barrier();                                               \
    if (ISSUE) {                                                                \
      __builtin_amdgcn_global_load_lds((glb_u32*)gp, dstA[(CUR) ^ 1], 16, 0, 0);\
      __builtin_amdgcn_global_load_lds((glb_u32*)(gp + ghalf), dstB[(CUR) ^ 1], \
                                       16, 0, 0);                               \
      gp += gstep;                                                              \
    }                                                                           \
    __builtin_amdgcn_sched_barrier(0);                                          \
    f32x4 stA[4], stB[4];                                                       \
    __builtin_amdgcn_s_setprio(1);                                              \
    _Pragma("unroll")                                                           \
    for (int jj = 0; jj < 4; ++jj) {                                            \
      U16x8 kf; kf.u4 = *(const uint4*)&Kt[CUR][(jj * 16 + l16) * 32 + sp];     \
      stA[jj] = __builtin_amdgcn_mfma_f32_16x16x32_bf16(kf.v, qf.v, zf, 0, 0, 0);\
    }                                                                           \
    _Pragma("unroll")                                                           \
    for (int jj = 0; jj < 4; ++jj) {                                            \
      U16x8 kf;                                                                 \
      kf.u4 = *(const uint4*)&Kt[CUR][2048 + (jj * 16 + l16) * 32 + sp];        \
      stB[jj] = __builtin_amdgcn_mfma_f32_16x16x32_bf16(kf.v, qf.v, zf, 0, 0, 0);\
    }                                                                           \
    __builtin_amdgcn_s_setprio(0);                                              \
    SOFTPV(stA, (&Vt[CUR][0]))                                                  \
    SOFTPV(stB, (&Vt[CUR][2048]))                                               \
  }

  // 32 tiles = 16 super-iterations: 14 rolled + 2 peeled (last stages none).
#pragma unroll 1
  for (int it = 0; it < 7; ++it) {
    ATTN_STEP(0, 1)
    ATTN_STEP(1, 1)
  }
  ATTN_STEP(0, 1)
  ATTN_STEP(1, 0)
#undef ATTN_STEP
#undef SOFTPV

  // Epilogue: bf16 pixel-major pO. pixel = i0 + (w>>2)*64 + (w&3)*16 + l16;
  // d = quad*4+r (o0) / 16+quad*4+r (o1) -> contiguous uint2 per half.
  int pix = i0 + (w >> 2) * 64 + (w & 3) * 16 + l16;
  unsigned short* pb = pOb + (((size_t)b * NPIX + pix) * 2 + chunk) * 256 + h * 32;
  uint2 s0, s1;
  s0.x = (unsigned)tobf(o0[0]) | ((unsigned)tobf(o0[1]) << 16);
  s0.y = (unsigned)tobf(o0[2]) | ((unsigned)tobf(o0[3]) << 16);
  s1.x = (unsigned)tobf(o1[0]) | ((unsigned)tobf(o1[1]) << 16);
  s1.y = (unsigned)tobf(o1[2]) | ((unsigned)tobf(o1[3]) << 16);
  *(uint2*)(pb + quad * 4) = s0;
  *(uint2*)(pb + 16 + quad * 4) = s1;

  int pr = bh * 64 + iblk * 2 + (w >> 2);
  int icol = (w & 3) * 16 + l16;
  if (quad == 0)
    pl[((size_t)chunk * 1024 + pr) * 64 + icol] = lacc[0];
}

// ---------------------------------------------------------------------------
// wout GEMM r12: pO is bf16 pixel-major -> per (k0) each lane reads ONE uint4
// per chunk (8 contiguous bf16 = the full fragment k-range k0+quad*8..+7).
// 16 x 16B vectorized loads replace 64 x 4B strided scalars. Identical k
// mapping (k = hh*32 + quad*8 + e) and identical truncation of the B-operand.
// ---------------------------------------------------------------------------
__global__ __launch_bounds__(256) void wout_kernel(
    const unsigned short* __restrict__ W, const unsigned short* __restrict__ pOb,
    const float* __restrict__ pl, const float* __restrict__ bias,
    const float* __restrict__ res, float* __restrict__ xres_t,
    float* __restrict__ part2p) {
  int t = threadIdx.x;
  int w = t >> 6, lane = t & 63, l16 = lane & 15, quad = lane >> 4;
  int p = blockIdx.x * 16 + l16;
  int b = p >> 12, n = p & 4095;
  int i = p & 63, iblk = (p >> 6) & 63;
  int ob = w * 64;
  float rinv8[8];
#pragma unroll
  for (int hh = 0; hh < 8; ++hh) {
    size_t pr = (size_t)(b * NHEAD + hh) * 64 + iblk;
    float l = pl[pr * 64 + i] + pl[(1024 + pr) * 64 + i];
    rinv8[hh] = 1.f / l;
  }
  const unsigned short* pb = pOb + (size_t)p * 2 * 256;  // p = b*4096+n
  f32x4 acc[4] = {};
#pragma unroll
  for (int k0 = 0; k0 < 256; k0 += 32) {
    U16x8 c0, c1;
    c0.u4 = *(const uint4*)(pb + k0 + quad * 8);          // chunk 0
    c1.u4 = *(const uint4*)(pb + 256 + k0 + quad * 8);    // chunk 1
    float rv = rinv8[k0 >> 5];
    U16x8 bfr;
#pragma unroll
    for (int u = 0; u < 4; ++u) {
      float va = (bf2f(c0.us[2 * u]) + bf2f(c1.us[2 * u])) * rv;
      float vb = (bf2f(c0.us[2 * u + 1]) + bf2f(c1.us[2 * u + 1])) * rv;
      bfr.u32[u] = packtrunc(va, vb);
    }
#pragma unroll
    for (int ot = 0; ot < 4; ++ot) {
      U16x8 af;
      af.u4 = *(const uint4*)(W + (size_t)(ob + ot * 16 + l16) * 256 + k0 + quad * 8);
      acc[ot] = __builtin_amdgcn_mfma_f32_16x16x32_bf16(af.v, bfr.v, acc[ot], 0, 0, 0);
    }
  }
  __shared__ float sb[256][4][2];
#pragma unroll
  for (int ot = 0; ot < 4; ++ot) {
    int oc = ob + ot * 16 + quad * 4;
    float s = 0.f, s2 = 0.f;
    float v4[4];
#pragma unroll
    for (int r = 0; r < 4; ++r) {
      float vv = acc[ot][r] + bias[oc + r] + res[((size_t)(b * NC + oc + r)) * NPIX + n];
      v4[r] = vv;
      s += vv; s2 += vv * vv;
    }
    *(float4*)&xres_t[(size_t)p * NC + oc] = make_float4(v4[0], v4[1], v4[2], v4[3]);
    sb[t][ot][0] = s; sb[t][ot][1] = s2;
  }
  __syncthreads();
  if (t < 32) {  // group g == t; channels [g*8, g*8+8)
    int ww = t >> 3, rem = t & 7, ot = rem >> 1, qp = rem & 1;
    float s = 0.f, s2 = 0.f;
#pragma unroll
    for (int q = 2 * qp; q < 2 * qp + 2; ++q)
      for (int l = 0; l < 16; ++l) {
        int tt = ww * 64 + q * 16 + l;
        s += sb[tt][ot][0]; s2 += sb[tt][ot][1];
      }
    size_t idx = ((size_t)(b * 32 + t) * 256 + (blockIdx.x & 255)) * 2;
    part2p[idx] = s; part2p[idx + 1] = s2;
  }
}

// ---------------------------------------------------------------------------
// MLP mega-kernel (r11 config, unchanged).
// ---------------------------------------------------------------------------
__global__ __launch_bounds__(256) void mlp_fused_kernel(
    const void* __restrict__ xraw, const float* __restrict__ xres_t,
    const float* __restrict__ gnst, const float* __restrict__ g2,
    const float* __restrict__ be2, const unsigned short* __restrict__ W1,
    const float* __restrict__ b1, const unsigned short* __restrict__ W2,
    const float* __restrict__ b2, void* __restrict__ dout) {
  int wbf = detect_bf(xraw);
  int t = threadIdx.x;
  int w = t >> 6, lane = t & 63, l16 = lane & 15, quad = lane >> 4;
  int p0 = blockIdx.x * 16;
  int b = p0 >> 12;
  __shared__ float Xs[16][261];
  __shared__ unsigned short Ys[16][264];
  {
    int p = t >> 4, cg = t & 15;  // coalesced: 16 consecutive t span one row
    int gg0 = (b * 32 + cg * 2) * 2;
    float m0 = gnst[gg0], i0 = gnst[gg0 + 1];
    float m1 = gnst[gg0 + 2], i1 = gnst[gg0 + 3];
    const float* src = xres_t + (size_t)(p0 + p) * NC + cg * 16;
    U16x8 lo, hi;
#pragma unroll
    for (int cc = 0; cc < 16; ++cc) {
      int c = cg * 16 + cc;
      float v = src[cc];
      Xs[p][c] = v;
      float mean = (cc < 8) ? m0 : m1;
      float si_ = (cc < 8) ? i0 : i1;
      float yv = (v - mean) * (g2[c] * si_) + be2[c];
      if (cc < 8) lo.us[cc] = tobf(yv); else hi.us[cc - 8] = tobf(yv);
    }
    *(uint4*)&Ys[p][cg * 16] = lo.u4;
    *(uint4*)&Ys[p][cg * 16 + 8] = hi.u4;
  }
  __syncthreads();
  f32x4 a1 = {0.f, 0.f, 0.f, 0.f};
#pragma unroll
  for (int k0 = 0; k0 < 256; k0 += 32) {
    U16x8 bfr; bfr.u4 = *(const uint4*)&Ys[l16][k0 + quad * 8];
    U16x8 af;
    af.u4 = *(const uint4*)(W1 + (size_t)(w * 16 + l16) * 256 + k0 + quad * 8);
    a1 = __builtin_amdgcn_mfma_f32_16x16x32_bf16(af.v, bfr.v, a1, 0, 0, 0);
  }
  __shared__ unsigned short Hs[16][72];
  {
    int oc = w * 16 + quad * 4;
    float h0 = geluf(a1[0] + b1[oc]),     h1 = geluf(a1[1] + b1[oc + 1]);
    float h2 = geluf(a1[2] + b1[oc + 2]), h3 = geluf(a1[3] + b1[oc + 3]);
    uint2 pk;
    pk.x = (unsigned)tobf(h0) | ((unsigned)tobf(h1) << 16);
    pk.y = (unsigned)tobf(h2) | ((unsigned)tobf(h3) << 16);
    *(uint2*)&Hs[l16][oc] = pk;
  }
  __syncthreads();
  f32x4 a2[4] = {};
#pragma unroll
  for (int k0 = 0; k0 < 64; k0 += 32) {
    U16x8 bfr; bfr.u4 = *(const uint4*)&Hs[l16][k0 + quad * 8];
#pragma unroll
    for (int ot = 0; ot < 4; ++ot) {
      U16x8 af;
      af.u4 = *(const uint4*)(W2 + (size_t)(w * 64 + ot * 16 + l16) * 64 + k0 + quad * 8);
      a2[ot] = __builtin_amdgcn_mfma_f32_16x16x32_bf16(af.v, bfr.v, a2[ot], 0, 0, 0);
    }
  }
  int n = (p0 & 4095) + l16;
#pragma unroll
  for (int ot = 0; ot < 4; ++ot) {
    int oc = w * 64 + ot * 16 + quad * 4;
#pragma unroll
    for (int r = 0; r < 4; ++r) {
      float v = a2[ot][r] + b2[oc + r] + Xs[l16][oc + r];
      size_t oidx = ((size_t)(b * NC + oc + r)) * NPIX + n;
      if (wbf) ((__hip_bfloat16*)dout)[oidx] = __float2bfloat16(v);
      else ((float*)dout)[oidx] = v;
    }
  }
}

// ---------------------------------------------------------------------------
// Launch pipeline: 7 kernels.
// ---------------------------------------------------------------------------
extern "C" void kernel_launch(void* const* d_in, const int* in_sizes, int n_in,
                              void* d_out, int out_size, void* d_ws, size_t ws_size,
                              hipStream_t stream) {
  float* ws = (float*)d_ws;
  size_t off = 16;
  float* x_f    = ws + off; off += (size_t)NB * NC * NPIX;
  float* wqkv_f = ws + off; off += 768 * 256;
  float* wout_f = ws + off; off += 256 * 256;
  float* bout_f = ws + off; off += 256;
  float* temp_f = ws + off; off += 8;
  float* g1_f   = ws + off; off += 256;
  float* be1_f  = ws + off; off += 256;
  float* g2_f   = ws + off; off += 256;
  float* be2_f  = ws + off; off += 256;
  float* wm1_f  = ws + off; off += 64 * 256;
  float* bm1_f  = ws + off; off += 64;
  float* wm2_f  = ws + off; off += 256 * 64;
  float* bm2_f  = ws + off; off += 256;
  float* xres   = ws + off; off += (size_t)NB * NC * NPIX;  // pixel-major [8192][256]
  unsigned short* qn     = (unsigned short*)(ws + off); off += 1048576;  // [16][4096][32]
  unsigned short* kn     = (unsigned short*)(ws + off); off += 1048576;  // [16][4096][32]
  unsigned short* vs     = (unsigned short*)(ws + off); off += 1048576;  // [2][256][4096]
  unsigned short* wqkv_b = (unsigned short*)(ws + off); off += 98304;
  unsigned short* wout_b = (unsigned short*)(ws + off); off += 32768;
  unsigned short* wm1_b  = (unsigned short*)(ws + off); off += 8192;
  unsigned short* wm2_b  = (unsigned short*)(ws + off); off += 8192;
  float* qscale = ws + off; off += 768;
  float* part1p = ws + off; off += 16384;   // [8192][2] GN1 block partials
  float* part2p = ws + off; off += 65536;   // [64 bg][256 blk][2] GN2 partials
  float* gnst1  = ws + off; off += 128;     // [64 groups][mean, rsqrt]
  float* gnst2  = ws + off; off += 128;
  float* pO     = ws + off; off += (size_t)NCHUNK * 1024 * 2048;  // used as bf16 (half)
  float* plb    = ws + off; off += (size_t)NCHUNK * 1024 * 64;
  (void)wqkv_f; (void)wout_f; (void)wm1_f; (void)wm2_f; (void)temp_f; (void)bm1_f;

  ConvArgs ca;
  int acc = 0;
  for (int i = 0; i < 13; ++i) {
    ca.src[i] = d_in[i];
    ca.off[i] = acc;
    acc += (i < n_in) ? in_sizes[i] : 0;
  }
  ca.off[13] = acc;
  conv_prep_kernel<<<(acc + 255) / 256, 256, 0, stream>>>(
      ca, x_f, acc, wqkv_b, wout_b, wm1_b, wm2_b, qscale, part1p);

  gn_stats_kernel<<<64, 64, 0, stream>>>(part1p, gnst1, 128);

  qkv_fused_kernel<<<dim3(512, 2), 256, 0, stream>>>(
      x_f, gnst1, g1_f, be1_f, wqkv_b, qscale, qn, kn, vs);

  attn15b_kernel<<<dim3(1024), 512, 0, stream>>>(
      qn, kn, vs, (unsigned short*)pO, plb);

  wout_kernel<<<512, 256, 0, stream>>>(
      wout_b, (unsigned short*)pO, plb, bout_f, x_f, xres, part2p);

  gn_stats_kernel<<<64, 64, 0, stream>>>(part2p, gnst2, 256);

  mlp_fused_kernel<<<512, 256, 0, stream>>>(
      d_in[0], xres, gnst2, g2_f, be2_f, wm1_b, bm1_f, wm2_b, bm2_f, d_out);
}